// Round 3
// baseline (1031.998 us; speedup 1.0000x reference)
//
#include <hip/hip_runtime.h>
#include <hip/hip_bf16.h>

constexpr int N = 50000;
constexpr int E = 800000;
constexpr int D = 128;
constexpr int H = 4;
constexpr int C = 32;
constexpr int L = 3;
constexpr int E2 = E + N;           // edges + self loops
constexpr float SLOPE = 0.2f;
constexpr float BN_EPS = 1e-5f;
constexpr int GR = 8;               // rows per block in GEMMs

// ---------- CSR build ----------
__global__ void count_kernel(const int* __restrict__ ei, int* __restrict__ counts) {
    int i = blockIdx.x * blockDim.x + threadIdx.x;
    if (i >= E2) return;
    int dst = (i < E) ? ei[E + i] : (i - E);
    atomicAdd(&counts[dst], 1);
}

__global__ __launch_bounds__(512) void scan_block_kernel(const int* __restrict__ counts,
                                                         int* __restrict__ row_ptr,
                                                         int* __restrict__ blk_sums) {
    __shared__ int s[512];
    int t = threadIdx.x;
    int i = blockIdx.x * 512 + t;
    int v = (i < N) ? counts[i] : 0;
    s[t] = v;
    __syncthreads();
    for (int off = 1; off < 512; off <<= 1) {
        int add = (t >= off) ? s[t - off] : 0;
        __syncthreads();
        s[t] += add;
        __syncthreads();
    }
    if (i < N) row_ptr[i] = s[t] - v;                 // exclusive within block
    if (t == 511) blk_sums[blockIdx.x] = s[511];
}

__global__ __launch_bounds__(128) void scan_sums_kernel(int* __restrict__ blk, int nb) {
    __shared__ int s[128];
    int t = threadIdx.x;
    int v = (t < nb) ? blk[t] : 0;
    s[t] = v;
    __syncthreads();
    for (int off = 1; off < 128; off <<= 1) {
        int add = (t >= off) ? s[t - off] : 0;
        __syncthreads();
        s[t] += add;
        __syncthreads();
    }
    if (t < nb) blk[t] = s[t] - v;                    // exclusive block offsets
}

__global__ void scan_add_kernel(int* __restrict__ row_ptr, const int* __restrict__ blk) {
    int i = blockIdx.x * blockDim.x + threadIdx.x;
    if (i < N) row_ptr[i] += blk[i >> 9];
    if (i == 0) row_ptr[N] = E2;
}

__global__ void scatter_kernel(const int* __restrict__ ei, const int* __restrict__ row_ptr,
                               int* __restrict__ wp, int* __restrict__ col_idx) {
    int i = blockIdx.x * blockDim.x + threadIdx.x;
    if (i >= E2) return;
    int src, dst;
    if (i < E) { src = ei[i]; dst = ei[E + i]; }
    else       { src = i - E; dst = i - E; }
    int pos = row_ptr[dst] + atomicAdd(&wp[dst], 1);
    col_idx[pos] = src;
}

// ---------- fused 3-matrix GEMM: xl = x@Wl, xr = x@Wr, res = x@Wres + bias ----------
__global__ __launch_bounds__(128) void gemm3_kernel(
        const float* __restrict__ x, const float* __restrict__ Wl,
        const float* __restrict__ Wr, const float* __restrict__ Wres,
        const float* __restrict__ bias, float* __restrict__ xl,
        float* __restrict__ xr, float* __restrict__ res) {
    __shared__ float xs[D][GR];                       // xs[k][r] : transposed row tile
    int t = threadIdx.x;
    int row0 = blockIdx.x * GR;
#pragma unroll
    for (int r = 0; r < GR; ++r) xs[t][r] = x[(row0 + r) * D + t];
    __syncthreads();
    float al[GR], ar[GR], as_[GR];
#pragma unroll
    for (int r = 0; r < GR; ++r) { al[r] = 0.f; ar[r] = 0.f; as_[r] = 0.f; }
    for (int k = 0; k < D; ++k) {
        float wl = Wl[k * D + t];
        float wr = Wr[k * D + t];
        float ws = Wres[k * D + t];
#pragma unroll
        for (int r = 0; r < GR; ++r) {
            float xv = xs[k][r];
            al[r]  = fmaf(xv, wl, al[r]);
            ar[r]  = fmaf(xv, wr, ar[r]);
            as_[r] = fmaf(xv, ws, as_[r]);
        }
    }
    float bv = bias[t];
#pragma unroll
    for (int r = 0; r < GR; ++r) {
        xl[(row0 + r) * D + t]  = al[r];
        xr[(row0 + r) * D + t]  = ar[r];
        res[(row0 + r) * D + t] = as_[r] + bv;
    }
}

// ---------- GATv2 aggregation with online softmax; y holds res in, agg+res out ----------
__global__ __launch_bounds__(128) void gat_kernel(
        const float* __restrict__ xl, const float* __restrict__ xr,
        float* __restrict__ y, const int* __restrict__ row_ptr,
        const int* __restrict__ col_idx, const float* __restrict__ att) {
    int v = blockIdx.x;
    int t = threadIdx.x;
    float xr_v = xr[v * D + t];
    float a_t = att[t];                               // att[h][c], h = t/32, c = t%32
    int beg = row_ptr[v], end = row_ptr[v + 1];
    float m = -INFINITY, l = 0.f, acc = 0.f;
    int u = col_idx[beg];                             // degree >= 1 (self loop)
    float xln = xl[u * D + t];
    for (int idx = beg; idx < end; ++idx) {
        float xlu = xln;
        if (idx + 1 < end) {                          // prefetch next source row
            int u2 = col_idx[idx + 1];
            xln = xl[u2 * D + t];
        }
        float pre = xlu + xr_v;
        pre = (pre > 0.f) ? pre : SLOPE * pre;
        float p = pre * a_t;
        // per-head reduction across the 32-lane group (wave=64, xor<=16 stays in-group)
        p += __shfl_xor(p, 1);
        p += __shfl_xor(p, 2);
        p += __shfl_xor(p, 4);
        p += __shfl_xor(p, 8);
        p += __shfl_xor(p, 16);
        float nm = fmaxf(m, p);
        float sc = __expf(m - nm);                    // 0 on first iter (m=-inf)
        float w  = __expf(p - nm);
        l   = l * sc + w;
        acc = fmaf(w, xlu, acc * sc);
        m = nm;
    }
    int o = v * D + t;
    y[o] = acc / l + y[o];                            // + res (+bias)
}

// ---------- BatchNorm ----------
__global__ __launch_bounds__(128) void bn_stats_kernel(const float* __restrict__ y,
                                                       float* __restrict__ sums) {
    int t = threadIdx.x;
    float s = 0.f, s2 = 0.f;
    for (int r = blockIdx.x; r < N; r += gridDim.x) {
        float v = y[r * D + t];
        s += v;
        s2 = fmaf(v, v, s2);
    }
    atomicAdd(&sums[t], s);
    atomicAdd(&sums[D + t], s2);
}

__global__ __launch_bounds__(128) void bn_finalize_kernel(const float* __restrict__ sums,
                                                          const float* __restrict__ gamma,
                                                          const float* __restrict__ beta,
                                                          float* __restrict__ ss) {
    int t = threadIdx.x;
    float mean = sums[t] * (1.0f / N);
    float var = sums[D + t] * (1.0f / N) - mean * mean;
    var = fmaxf(var, 0.f);
    float sc = gamma[t] * rsqrtf(var + BN_EPS);
    ss[t] = sc;
    ss[D + t] = beta[t] - mean * sc;
}

__global__ void bn_apply_kernel(const float* __restrict__ y, const float* __restrict__ ss,
                                float* __restrict__ xout) {
    int i = blockIdx.x * blockDim.x + threadIdx.x;
    if (i >= N * D) return;
    int c = i & (D - 1);
    float v = fmaf(y[i], ss[c], ss[D + c]);
    xout[i] = (v > 0.f) ? v : SLOPE * v;              // LeakyReLU
}

// ---------- final linear -> fp32 out ----------
__global__ __launch_bounds__(128) void gemm_out_kernel(
        const float* __restrict__ x, const float* __restrict__ W,
        const float* __restrict__ b, float* __restrict__ out) {
    __shared__ float xs[D][GR];
    int t = threadIdx.x;
    int row0 = blockIdx.x * GR;
#pragma unroll
    for (int r = 0; r < GR; ++r) xs[t][r] = x[(row0 + r) * D + t];
    __syncthreads();
    float acc[GR];
#pragma unroll
    for (int r = 0; r < GR; ++r) acc[r] = 0.f;
    for (int k = 0; k < D; ++k) {
        float w = W[k * D + t];
#pragma unroll
        for (int r = 0; r < GR; ++r) acc[r] = fmaf(xs[k][r], w, acc[r]);
    }
    float bv = b[t];
#pragma unroll
    for (int r = 0; r < GR; ++r)
        out[(row0 + r) * D + t] = acc[r] + bv;
}

extern "C" void kernel_launch(void* const* d_in, const int* in_sizes, int n_in,
                              void* d_out, int out_size, void* d_ws, size_t ws_size,
                              hipStream_t stream) {
    const float* x_in  = (const float*)d_in[0];
    const int*   ei    = (const int*)d_in[1];
    const float* Wl    = (const float*)d_in[2];
    const float* Wr    = (const float*)d_in[3];
    const float* att   = (const float*)d_in[4];
    const float* bias  = (const float*)d_in[5];
    const float* Wres  = (const float*)d_in[6];
    const float* gamma = (const float*)d_in[7];
    const float* beta  = (const float*)d_in[8];
    const float* Wout  = (const float*)d_in[9];
    const float* bout  = (const float*)d_in[10];
    float* out = (float*)d_out;

    char* ws = (char*)d_ws;
    size_t off = 0;
    auto alloc = [&](size_t bytes) {
        void* p = ws + off;
        off = (off + bytes + 255) & ~(size_t)255;
        return p;
    };
    float* xf       = (float*)alloc((size_t)N * D * sizeof(float));
    float* xl       = (float*)alloc((size_t)N * D * sizeof(float));
    float* xr       = (float*)alloc((size_t)N * D * sizeof(float));
    float* y        = (float*)alloc((size_t)N * D * sizeof(float));
    int*   row_ptr  = (int*)alloc((size_t)(N + 1) * sizeof(int));
    int*   col_idx  = (int*)alloc((size_t)E2 * sizeof(int));
    int*   counts   = (int*)alloc((size_t)N * sizeof(int));   // reused as write ptr
    int*   blk_sums = (int*)alloc(128 * sizeof(int));
    float* sums     = (float*)alloc(2 * D * sizeof(float));
    float* ss       = (float*)alloc(2 * D * sizeof(float));

    const int NB = (N + 511) / 512;                  // 98 scan blocks

    // CSR build
    hipMemsetAsync(counts, 0, (size_t)N * sizeof(int), stream);
    count_kernel<<<(E2 + 255) / 256, 256, 0, stream>>>(ei, counts);
    scan_block_kernel<<<NB, 512, 0, stream>>>(counts, row_ptr, blk_sums);
    scan_sums_kernel<<<1, 128, 0, stream>>>(blk_sums, NB);
    scan_add_kernel<<<(N + 255) / 256, 256, 0, stream>>>(row_ptr, blk_sums);
    hipMemsetAsync(counts, 0, (size_t)N * sizeof(int), stream);
    scatter_kernel<<<(E2 + 255) / 256, 256, 0, stream>>>(ei, row_ptr, counts, col_idx);

    for (int i = 0; i < L; ++i) {
        const float* xin = (i == 0) ? x_in : xf;
        gemm3_kernel<<<N / GR, 128, 0, stream>>>(xin, Wl + (size_t)i * D * D,
                                                 Wr + (size_t)i * D * D,
                                                 Wres + (size_t)i * D * D,
                                                 bias + (size_t)i * D, xl, xr, y);
        gat_kernel<<<N, 128, 0, stream>>>(xl, xr, y, row_ptr, col_idx,
                                          att + (size_t)i * H * C);
        hipMemsetAsync(sums, 0, 2 * D * sizeof(float), stream);
        bn_stats_kernel<<<256, 128, 0, stream>>>(y, sums);
        bn_finalize_kernel<<<1, 128, 0, stream>>>(sums, gamma + (size_t)i * D,
                                                  beta + (size_t)i * D, ss);
        bn_apply_kernel<<<(N * D + 255) / 256, 256, 0, stream>>>(y, ss, xf);
    }

    gemm_out_kernel<<<N / GR, 128, 0, stream>>>(xf, Wout, bout, out);
}

// Round 4
// 922.010 us; speedup vs baseline: 1.1193x; 1.1193x over previous
//
#include <hip/hip_runtime.h>

constexpr int N = 50000;
constexpr int E = 800000;
constexpr int D = 128;
constexpr int H = 4;
constexpr int C = 32;
constexpr int L = 3;
constexpr int E2 = E + N;           // edges + self loops
constexpr float SLOPE = 0.2f;
constexpr float BN_EPS = 1e-5f;
constexpr int GR = 8;               // rows per block in GEMMs

// ---------- CSR build ----------
__global__ void count_kernel(const int* __restrict__ ei, int* __restrict__ counts) {
    int i = blockIdx.x * blockDim.x + threadIdx.x;
    if (i >= E2) return;
    int dst = (i < E) ? ei[E + i] : (i - E);
    atomicAdd(&counts[dst], 1);
}

__global__ __launch_bounds__(512) void scan_block_kernel(const int* __restrict__ counts,
                                                         int* __restrict__ row_ptr,
                                                         int* __restrict__ blk_sums) {
    __shared__ int s[512];
    int t = threadIdx.x;
    int i = blockIdx.x * 512 + t;
    int v = (i < N) ? counts[i] : 0;
    s[t] = v;
    __syncthreads();
    for (int off = 1; off < 512; off <<= 1) {
        int add = (t >= off) ? s[t - off] : 0;
        __syncthreads();
        s[t] += add;
        __syncthreads();
    }
    if (i < N) row_ptr[i] = s[t] - v;                 // exclusive within block
    if (t == 511) blk_sums[blockIdx.x] = s[511];
}

__global__ __launch_bounds__(128) void scan_sums_kernel(int* __restrict__ blk, int nb) {
    __shared__ int s[128];
    int t = threadIdx.x;
    int v = (t < nb) ? blk[t] : 0;
    s[t] = v;
    __syncthreads();
    for (int off = 1; off < 128; off <<= 1) {
        int add = (t >= off) ? s[t - off] : 0;
        __syncthreads();
        s[t] += add;
        __syncthreads();
    }
    if (t < nb) blk[t] = s[t] - v;                    // exclusive block offsets
}

__global__ void scan_add_kernel(int* __restrict__ row_ptr, const int* __restrict__ blk) {
    int i = blockIdx.x * blockDim.x + threadIdx.x;
    if (i < N) row_ptr[i] += blk[i >> 9];
    if (i == 0) row_ptr[N] = E2;
}

__global__ void scatter_kernel(const int* __restrict__ ei, const int* __restrict__ row_ptr,
                               int* __restrict__ wp, int* __restrict__ col_idx) {
    int i = blockIdx.x * blockDim.x + threadIdx.x;
    if (i >= E2) return;
    int src, dst;
    if (i < E) { src = ei[i]; dst = ei[E + i]; }
    else       { src = i - E; dst = i - E; }
    int pos = row_ptr[dst] + atomicAdd(&wp[dst], 1);
    col_idx[pos] = src;
}

// ---------- fused 3-matrix GEMM (+ optional BN/LeakyReLU on the x-load) ----------
// xl = f(x)@Wl, xr = f(x)@Wr, res = f(x)@Wres + bias, f = leaky(bn) if ss else id.
// May run in-place (x == res): each block reads only its own GR rows into LDS
// (barrier) before writing them back, so no cross-block hazard.
__global__ __launch_bounds__(128) void gemm3_kernel(
        const float* x, const float* __restrict__ ss,
        const float* __restrict__ Wl, const float* __restrict__ Wr,
        const float* __restrict__ Wres, const float* __restrict__ bias,
        float* __restrict__ xl, float* __restrict__ xr, float* res) {
    __shared__ float2 xs[D][GR / 2];                  // xs[k][j] = rows (2j, 2j+1)
    int t = threadIdx.x;
    int row0 = blockIdx.x * GR;
    float sc = 1.f, sh = 0.f;
    if (ss) { sc = ss[t]; sh = ss[D + t]; }
#pragma unroll
    for (int r = 0; r < GR; ++r) {
        float v = x[(row0 + r) * D + t];
        if (ss) { v = fmaf(v, sc, sh); v = fmaxf(v, SLOPE * v); }
        ((float*)&xs[t][0])[r] = v;
    }
    __syncthreads();
    float2 al[GR / 2], ar[GR / 2], as_[GR / 2];
#pragma unroll
    for (int j = 0; j < GR / 2; ++j) {
        al[j] = make_float2(0.f, 0.f);
        ar[j] = make_float2(0.f, 0.f);
        as_[j] = make_float2(0.f, 0.f);
    }
    for (int k = 0; k < D; ++k) {
        float wl = Wl[k * D + t];
        float wr = Wr[k * D + t];
        float ws = Wres[k * D + t];
#pragma unroll
        for (int j = 0; j < GR / 2; ++j) {
            float2 xv = xs[k][j];
            al[j].x  = fmaf(xv.x, wl, al[j].x);
            al[j].y  = fmaf(xv.y, wl, al[j].y);
            ar[j].x  = fmaf(xv.x, wr, ar[j].x);
            ar[j].y  = fmaf(xv.y, wr, ar[j].y);
            as_[j].x = fmaf(xv.x, ws, as_[j].x);
            as_[j].y = fmaf(xv.y, ws, as_[j].y);
        }
    }
    float bv = bias[t];
#pragma unroll
    for (int j = 0; j < GR / 2; ++j) {
        xl[(row0 + 2 * j) * D + t]     = al[j].x;
        xl[(row0 + 2 * j + 1) * D + t] = al[j].y;
        xr[(row0 + 2 * j) * D + t]     = ar[j].x;
        xr[(row0 + 2 * j + 1) * D + t] = ar[j].y;
        res[(row0 + 2 * j) * D + t]     = as_[j].x + bv;
        res[(row0 + 2 * j + 1) * D + t] = as_[j].y + bv;
    }
}

// ---------- GATv2 aggregation, one wave per node, float2 per lane ----------
__global__ __launch_bounds__(128) void gat_kernel(
        const float* __restrict__ xl, const float* __restrict__ xr,
        float* y, const int* __restrict__ row_ptr,
        const int* __restrict__ col_idx, const float* __restrict__ att) {
    int wave = threadIdx.x >> 6;
    int lane = threadIdx.x & 63;
    int v = blockIdx.x * 2 + wave;
    if (v >= N) return;
    const float2* xl2 = (const float2*)xl;
    float2 xr_v = ((const float2*)xr)[v * 64 + lane];
    float2 a2 = ((const float2*)att)[lane];           // channels 2l,2l+1; head = lane/16
    int beg = row_ptr[v], end = row_ptr[v + 1];
    float m = -INFINITY, l = 0.f;
    float2 acc = make_float2(0.f, 0.f);
    int u = col_idx[beg];                             // degree >= 1 (self loop)
    float2 xln = xl2[(size_t)u * 64 + lane];
    for (int idx = beg; idx < end; ++idx) {
        float2 xlu = xln;
        if (idx + 1 < end) {                          // prefetch next source row
            int u2 = col_idx[idx + 1];
            xln = xl2[(size_t)u2 * 64 + lane];
        }
        float2 pre;
        pre.x = xlu.x + xr_v.x;
        pre.y = xlu.y + xr_v.y;
        pre.x = fmaxf(pre.x, SLOPE * pre.x);          // leaky (slope<1)
        pre.y = fmaxf(pre.y, SLOPE * pre.y);
        float p = fmaf(pre.x, a2.x, pre.y * a2.y);    // horizontal first
        // reduce across the 16-lane head group
        p += __shfl_xor(p, 1);
        p += __shfl_xor(p, 2);
        p += __shfl_xor(p, 4);
        p += __shfl_xor(p, 8);
        float nm = fmaxf(m, p);
        float scl = __expf(m - nm);                   // 0 on first iter (m=-inf)
        float w   = __expf(p - nm);
        l = l * scl + w;
        acc.x = fmaf(w, xlu.x, acc.x * scl);
        acc.y = fmaf(w, xlu.y, acc.y * scl);
        m = nm;
    }
    float rl = 1.f / l;
    int o = v * 64 + lane;
    float2 yv = ((const float2*)y)[o];
    yv.x = fmaf(acc.x, rl, yv.x);                     // agg + res(+bias)
    yv.y = fmaf(acc.y, rl, yv.y);
    ((float2*)y)[o] = yv;
}

// ---------- BatchNorm stats ----------
__global__ __launch_bounds__(128) void bn_stats_kernel(const float* __restrict__ y,
                                                       float* __restrict__ sums) {
    int t = threadIdx.x;
    float s = 0.f, s2 = 0.f;
    for (int r = blockIdx.x; r < N; r += gridDim.x) {
        float v = y[r * D + t];
        s += v;
        s2 = fmaf(v, v, s2);
    }
    atomicAdd(&sums[t], s);
    atomicAdd(&sums[D + t], s2);
}

__global__ __launch_bounds__(128) void bn_finalize_kernel(const float* __restrict__ sums,
                                                          const float* __restrict__ gamma,
                                                          const float* __restrict__ beta,
                                                          float* __restrict__ ss) {
    int t = threadIdx.x;
    float mean = sums[t] * (1.0f / N);
    float var = sums[D + t] * (1.0f / N) - mean * mean;
    var = fmaxf(var, 0.f);
    float sc = gamma[t] * rsqrtf(var + BN_EPS);
    ss[t] = sc;
    ss[D + t] = beta[t] - mean * sc;
}

// ---------- final linear (+ BN/LeakyReLU on the x-load) -> fp32 out ----------
__global__ __launch_bounds__(128) void gemm_out_kernel(
        const float* __restrict__ x, const float* __restrict__ ss,
        const float* __restrict__ W, const float* __restrict__ b,
        float* __restrict__ out) {
    __shared__ float2 xs[D][GR / 2];
    int t = threadIdx.x;
    int row0 = blockIdx.x * GR;
    float sc = ss[t], sh = ss[D + t];
#pragma unroll
    for (int r = 0; r < GR; ++r) {
        float v = x[(row0 + r) * D + t];
        v = fmaf(v, sc, sh);
        v = fmaxf(v, SLOPE * v);
        ((float*)&xs[t][0])[r] = v;
    }
    __syncthreads();
    float2 acc[GR / 2];
#pragma unroll
    for (int j = 0; j < GR / 2; ++j) acc[j] = make_float2(0.f, 0.f);
    for (int k = 0; k < D; ++k) {
        float w = W[k * D + t];
#pragma unroll
        for (int j = 0; j < GR / 2; ++j) {
            float2 xv = xs[k][j];
            acc[j].x = fmaf(xv.x, w, acc[j].x);
            acc[j].y = fmaf(xv.y, w, acc[j].y);
        }
    }
    float bv = b[t];
#pragma unroll
    for (int j = 0; j < GR / 2; ++j) {
        out[(row0 + 2 * j) * D + t]     = acc[j].x + bv;
        out[(row0 + 2 * j + 1) * D + t] = acc[j].y + bv;
    }
}

extern "C" void kernel_launch(void* const* d_in, const int* in_sizes, int n_in,
                              void* d_out, int out_size, void* d_ws, size_t ws_size,
                              hipStream_t stream) {
    const float* x_in  = (const float*)d_in[0];
    const int*   ei    = (const int*)d_in[1];
    const float* Wl    = (const float*)d_in[2];
    const float* Wr    = (const float*)d_in[3];
    const float* att   = (const float*)d_in[4];
    const float* bias  = (const float*)d_in[5];
    const float* Wres  = (const float*)d_in[6];
    const float* gamma = (const float*)d_in[7];
    const float* beta  = (const float*)d_in[8];
    const float* Wout  = (const float*)d_in[9];
    const float* bout  = (const float*)d_in[10];
    float* out = (float*)d_out;

    char* ws = (char*)d_ws;
    size_t off = 0;
    auto alloc = [&](size_t bytes) {
        void* p = ws + off;
        off = (off + bytes + 255) & ~(size_t)255;
        return p;
    };
    float* xl       = (float*)alloc((size_t)N * D * sizeof(float));
    float* xr       = (float*)alloc((size_t)N * D * sizeof(float));
    float* y        = (float*)alloc((size_t)N * D * sizeof(float));
    int*   row_ptr  = (int*)alloc((size_t)(N + 1) * sizeof(int));
    int*   col_idx  = (int*)alloc((size_t)E2 * sizeof(int));
    int*   counts   = (int*)alloc((size_t)N * sizeof(int));   // reused as write ptr
    int*   blk_sums = (int*)alloc(128 * sizeof(int));
    float* sums     = (float*)alloc(2 * D * sizeof(float));
    float* ss       = (float*)alloc(2 * D * sizeof(float));

    const int NB = (N + 511) / 512;                  // 98 scan blocks

    // CSR build
    hipMemsetAsync(counts, 0, (size_t)N * sizeof(int), stream);
    count_kernel<<<(E2 + 255) / 256, 256, 0, stream>>>(ei, counts);
    scan_block_kernel<<<NB, 512, 0, stream>>>(counts, row_ptr, blk_sums);
    scan_sums_kernel<<<1, 128, 0, stream>>>(blk_sums, NB);
    scan_add_kernel<<<(N + 255) / 256, 256, 0, stream>>>(row_ptr, blk_sums);
    hipMemsetAsync(counts, 0, (size_t)N * sizeof(int), stream);
    scatter_kernel<<<(E2 + 255) / 256, 256, 0, stream>>>(ei, row_ptr, counts, col_idx);

    for (int i = 0; i < L; ++i) {
        const float* xin = (i == 0) ? x_in : y;      // in-place for layers 1,2
        const float* ssi = (i == 0) ? nullptr : ss;  // BN(i-1)+leaky fused into load
        gemm3_kernel<<<N / GR, 128, 0, stream>>>(xin, ssi,
                                                 Wl + (size_t)i * D * D,
                                                 Wr + (size_t)i * D * D,
                                                 Wres + (size_t)i * D * D,
                                                 bias + (size_t)i * D, xl, xr, y);
        gat_kernel<<<N / 2, 128, 0, stream>>>(xl, xr, y, row_ptr, col_idx,
                                              att + (size_t)i * H * C);
        hipMemsetAsync(sums, 0, 2 * D * sizeof(float), stream);
        bn_stats_kernel<<<256, 128, 0, stream>>>(y, sums);
        bn_finalize_kernel<<<1, 128, 0, stream>>>(sums, gamma + (size_t)i * D,
                                                  beta + (size_t)i * D, ss);
    }

    gemm_out_kernel<<<N / GR, 128, 0, stream>>>(y, ss, Wout, bout, out);
}

// Round 5
// 920.888 us; speedup vs baseline: 1.1207x; 1.0012x over previous
//
#include <hip/hip_runtime.h>
#include <hip/hip_bf16.h>

constexpr int N = 50000;
constexpr int E = 800000;
constexpr int D = 128;
constexpr int H = 4;
constexpr int C = 32;
constexpr int L = 3;
constexpr int E2 = E + N;           // edges + self loops
constexpr float SLOPE = 0.2f;
constexpr float BN_EPS = 1e-5f;
constexpr int NPAD = 50048;         // 782 * 64

typedef __attribute__((ext_vector_type(8))) short bf16x8_t;   // 8 bf16 (4 VGPRs)
typedef __attribute__((ext_vector_type(4))) float f32x4_t;    // MFMA C/D

using hbf = __hip_bfloat16;

// ---------- CSR build ----------
__global__ void count_kernel(const int* __restrict__ ei, int* __restrict__ counts) {
    int i = blockIdx.x * blockDim.x + threadIdx.x;
    if (i >= E2) return;
    int dst = (i < E) ? ei[E + i] : (i - E);
    atomicAdd(&counts[dst], 1);
}

__global__ __launch_bounds__(512) void scan_block_kernel(const int* __restrict__ counts,
                                                         int* __restrict__ row_ptr,
                                                         int* __restrict__ blk_sums) {
    __shared__ int s[512];
    int t = threadIdx.x;
    int i = blockIdx.x * 512 + t;
    int v = (i < N) ? counts[i] : 0;
    s[t] = v;
    __syncthreads();
    for (int off = 1; off < 512; off <<= 1) {
        int add = (t >= off) ? s[t - off] : 0;
        __syncthreads();
        s[t] += add;
        __syncthreads();
    }
    if (i < N) row_ptr[i] = s[t] - v;                 // exclusive within block
    if (t == 511) blk_sums[blockIdx.x] = s[511];
}

__global__ __launch_bounds__(128) void scan_sums_kernel(int* __restrict__ blk, int nb) {
    __shared__ int s[128];
    int t = threadIdx.x;
    int v = (t < nb) ? blk[t] : 0;
    s[t] = v;
    __syncthreads();
    for (int off = 1; off < 128; off <<= 1) {
        int add = (t >= off) ? s[t - off] : 0;
        __syncthreads();
        s[t] += add;
        __syncthreads();
    }
    if (t < nb) blk[t] = s[t] - v;                    // exclusive block offsets
}

__global__ void scan_add_kernel(int* __restrict__ row_ptr, const int* __restrict__ blk) {
    int i = blockIdx.x * blockDim.x + threadIdx.x;
    if (i < N) row_ptr[i] += blk[i >> 9];
    if (i == 0) row_ptr[N] = E2;
}

__global__ void scatter_kernel(const int* __restrict__ ei, const int* __restrict__ row_ptr,
                               int* __restrict__ wp, int* __restrict__ col_idx) {
    int i = blockIdx.x * blockDim.x + threadIdx.x;
    if (i >= E2) return;
    int src, dst;
    if (i < E) { src = ei[i]; dst = ei[E + i]; }
    else       { src = i - E; dst = i - E; }
    int pos = row_ptr[dst] + atomicAdd(&wp[dst], 1);
    col_idx[pos] = src;
}

// ---------- pack all 10 weight matrices into MFMA B-fragment order, hi/lo bf16 ----------
// B frag for 16x16x32: lane holds B[k = ks*32 + (lane>>4)*8 + j][n = nb*16 + (lane&15)],
// j=0..7. Packed index: (mat*2048 + (ks*8+nb)*64 + lane)*8 + j  -> lane-contiguous 16B.
__global__ __launch_bounds__(256) void pack_w_kernel(
        const float* __restrict__ Wl, const float* __restrict__ Wr,
        const float* __restrict__ Wres, const float* __restrict__ Wout,
        hbf* __restrict__ Wph, hbf* __restrict__ Wpl) {
    int gid = blockIdx.x * 256 + threadIdx.x;        // 10 * 16384
    int mat = gid >> 14;
    int d = gid & 16383;
    const float* W;
    if (mat < 3)      W = Wl + (size_t)mat * 16384;
    else if (mat < 6) W = Wr + (size_t)(mat - 3) * 16384;
    else if (mat < 9) W = Wres + (size_t)(mat - 6) * 16384;
    else              W = Wout;
    int j = d & 7, lane = (d >> 3) & 63, nb = (d >> 9) & 7, ks = d >> 12;
    int k = ks * 32 + ((lane >> 4) * 8) + j;
    int n = nb * 16 + (lane & 15);
    float w = W[k * D + n];
    hbf hi = __float2bfloat16(w);
    hbf lo = __float2bfloat16(w - __bfloat162float(hi));
    Wph[gid] = hi;
    Wpl[gid] = lo;
}

// ---------- prep: BN+leaky (optional) then split fp32 -> bf16 hi/lo, pad rows zeroed ----------
__global__ void prep_x_kernel(const float* __restrict__ x, const float* __restrict__ ss,
                              hbf* __restrict__ xh, hbf* __restrict__ xlo) {
    int i = blockIdx.x * blockDim.x + threadIdx.x;   // over NPAD*D
    if (i >= NPAD * D) return;
    float v = 0.f;
    if (i < N * D) {
        v = x[i];
        if (ss) {
            int c = i & (D - 1);
            v = fmaf(v, ss[c], ss[D + c]);
            v = fmaxf(v, SLOPE * v);
        }
    }
    hbf hi = __float2bfloat16(v);
    xh[i] = hi;
    xlo[i] = __float2bfloat16(v - __bfloat162float(hi));
}

// ---------- fused 3-matrix MFMA GEMM: xl = X@Wl, xr = X@Wr, y = X@Wres + bias ----------
// bf16 split: X@W ~= Xh@Wh + Xl@Wh + Xh@Wl (error ~2^-17 rel).
__global__ __launch_bounds__(256) void gemm3_mfma_kernel(
        const hbf* __restrict__ xh, const hbf* __restrict__ xlo,
        const hbf* __restrict__ Wph, const hbf* __restrict__ Wpl,
        int mL, int mR, int mS, const float* __restrict__ bias,
        float* __restrict__ xl, float* __restrict__ xr, float* __restrict__ y) {
    int wave = threadIdx.x >> 6;
    int lane = threadIdx.x & 63;
    int m0 = blockIdx.x * 64 + wave * 16;
    int arow = m0 + (lane & 15);
    int aoff = lane >> 4;                             // k-chunk within A frag
    const bf16x8_t* XH = (const bf16x8_t*)xh;         // 16 frags per row
    const bf16x8_t* XL = (const bf16x8_t*)xlo;
    const bf16x8_t* BH = (const bf16x8_t*)Wph;        // 2048 frags per matrix
    const bf16x8_t* BL = (const bf16x8_t*)Wpl;

    f32x4_t aL[8], aR[8], aS[8];
#pragma unroll
    for (int nb = 0; nb < 8; ++nb) {
        aL[nb] = (f32x4_t)0.f; aR[nb] = (f32x4_t)0.f; aS[nb] = (f32x4_t)0.f;
    }
    for (int ks = 0; ks < 4; ++ks) {
        int afrag = arow * 16 + ks * 4 + aoff;
        bf16x8_t ah = XH[afrag];
        bf16x8_t al = XL[afrag];
#pragma unroll
        for (int nb = 0; nb < 8; ++nb) {
            int bidx = (ks * 8 + nb) * 64 + lane;
            bf16x8_t bh, bl;
            bh = BH[mL * 2048 + bidx]; bl = BL[mL * 2048 + bidx];
            aL[nb] = __builtin_amdgcn_mfma_f32_16x16x32_bf16(ah, bh, aL[nb], 0, 0, 0);
            aL[nb] = __builtin_amdgcn_mfma_f32_16x16x32_bf16(al, bh, aL[nb], 0, 0, 0);
            aL[nb] = __builtin_amdgcn_mfma_f32_16x16x32_bf16(ah, bl, aL[nb], 0, 0, 0);
            bh = BH[mR * 2048 + bidx]; bl = BL[mR * 2048 + bidx];
            aR[nb] = __builtin_amdgcn_mfma_f32_16x16x32_bf16(ah, bh, aR[nb], 0, 0, 0);
            aR[nb] = __builtin_amdgcn_mfma_f32_16x16x32_bf16(al, bh, aR[nb], 0, 0, 0);
            aR[nb] = __builtin_amdgcn_mfma_f32_16x16x32_bf16(ah, bl, aR[nb], 0, 0, 0);
            bh = BH[mS * 2048 + bidx]; bl = BL[mS * 2048 + bidx];
            aS[nb] = __builtin_amdgcn_mfma_f32_16x16x32_bf16(ah, bh, aS[nb], 0, 0, 0);
            aS[nb] = __builtin_amdgcn_mfma_f32_16x16x32_bf16(al, bh, aS[nb], 0, 0, 0);
            aS[nb] = __builtin_amdgcn_mfma_f32_16x16x32_bf16(ah, bl, aS[nb], 0, 0, 0);
        }
    }
    // C/D layout: col = lane&15, row = (lane>>4)*4 + r
    int col = lane & 15;
    int rowq = m0 + (lane >> 4) * 4;
#pragma unroll
    for (int nb = 0; nb < 8; ++nb) {
        int n = nb * 16 + col;
        float bv = bias[n];
#pragma unroll
        for (int r = 0; r < 4; ++r) {
            int row = rowq + r;
            if (row < N) {
                xl[row * D + n] = aL[nb][r];
                xr[row * D + n] = aR[nb][r];
                y[row * D + n]  = aS[nb][r] + bv;
            }
        }
    }
}

// ---------- final linear via MFMA: out = X@Wout + bout ----------
__global__ __launch_bounds__(256) void gemm_out_mfma_kernel(
        const hbf* __restrict__ xh, const hbf* __restrict__ xlo,
        const hbf* __restrict__ Wph, const hbf* __restrict__ Wpl,
        const float* __restrict__ b, float* __restrict__ out) {
    int wave = threadIdx.x >> 6;
    int lane = threadIdx.x & 63;
    int m0 = blockIdx.x * 64 + wave * 16;
    int arow = m0 + (lane & 15);
    int aoff = lane >> 4;
    const bf16x8_t* XH = (const bf16x8_t*)xh;
    const bf16x8_t* XL = (const bf16x8_t*)xlo;
    const bf16x8_t* BH = (const bf16x8_t*)Wph + 9 * 2048;   // matrix 9 = Wout
    const bf16x8_t* BL = (const bf16x8_t*)Wpl + 9 * 2048;

    f32x4_t acc[8];
#pragma unroll
    for (int nb = 0; nb < 8; ++nb) acc[nb] = (f32x4_t)0.f;
    for (int ks = 0; ks < 4; ++ks) {
        int afrag = arow * 16 + ks * 4 + aoff;
        bf16x8_t ah = XH[afrag];
        bf16x8_t al = XL[afrag];
#pragma unroll
        for (int nb = 0; nb < 8; ++nb) {
            int bidx = (ks * 8 + nb) * 64 + lane;
            bf16x8_t bh = BH[bidx], bl = BL[bidx];
            acc[nb] = __builtin_amdgcn_mfma_f32_16x16x32_bf16(ah, bh, acc[nb], 0, 0, 0);
            acc[nb] = __builtin_amdgcn_mfma_f32_16x16x32_bf16(al, bh, acc[nb], 0, 0, 0);
            acc[nb] = __builtin_amdgcn_mfma_f32_16x16x32_bf16(ah, bl, acc[nb], 0, 0, 0);
        }
    }
    int col = lane & 15;
    int rowq = m0 + (lane >> 4) * 4;
#pragma unroll
    for (int nb = 0; nb < 8; ++nb) {
        int n = nb * 16 + col;
        float bv = b[n];
#pragma unroll
        for (int r = 0; r < 4; ++r) {
            int row = rowq + r;
            if (row < N) out[row * D + n] = acc[nb][r] + bv;
        }
    }
}

// ---------- GATv2 aggregation, one wave per node, float2/lane, 2-edge unroll ----------
__global__ __launch_bounds__(128) void gat_kernel(
        const float* __restrict__ xl, const float* __restrict__ xr,
        float* y, const int* __restrict__ row_ptr,
        const int* __restrict__ col_idx, const float* __restrict__ att) {
    int wave = threadIdx.x >> 6;
    int lane = threadIdx.x & 63;
    int v = blockIdx.x * 2 + wave;
    const float2* xl2 = (const float2*)xl;
    float2 xr_v = ((const float2*)xr)[v * 64 + lane];
    float2 a2 = ((const float2*)att)[lane];           // channels 2l,2l+1; head = lane/16
    int beg = row_ptr[v], end = row_ptr[v + 1];
    float m = -INFINITY, l = 0.f;
    float2 acc = make_float2(0.f, 0.f);
    float2 x0 = xl2[(size_t)col_idx[beg] * 64 + lane];            // degree >= 1
    float2 x1 = make_float2(0.f, 0.f);
    if (beg + 1 < end) x1 = xl2[(size_t)col_idx[beg + 1] * 64 + lane];
    int idx = beg;
    for (; idx + 1 < end; idx += 2) {
        float2 xa = x0, xb = x1;
        if (idx + 2 < end) x0 = xl2[(size_t)col_idx[idx + 2] * 64 + lane];
        if (idx + 3 < end) x1 = xl2[(size_t)col_idx[idx + 3] * 64 + lane];
        float2 pa, pb;
        pa.x = xa.x + xr_v.x; pa.y = xa.y + xr_v.y;
        pb.x = xb.x + xr_v.x; pb.y = xb.y + xr_v.y;
        pa.x = fmaxf(pa.x, SLOPE * pa.x); pa.y = fmaxf(pa.y, SLOPE * pa.y);
        pb.x = fmaxf(pb.x, SLOPE * pb.x); pb.y = fmaxf(pb.y, SLOPE * pb.y);
        float sa = fmaf(pa.x, a2.x, pa.y * a2.y);
        float sb = fmaf(pb.x, a2.x, pb.y * a2.y);
        sa += __shfl_xor(sa, 1);  sb += __shfl_xor(sb, 1);
        sa += __shfl_xor(sa, 2);  sb += __shfl_xor(sb, 2);
        sa += __shfl_xor(sa, 4);  sb += __shfl_xor(sb, 4);
        sa += __shfl_xor(sa, 8);  sb += __shfl_xor(sb, 8);
        float nm = fmaxf(m, fmaxf(sa, sb));
        float scl = __expf(m - nm);                   // 0 on first iter (m=-inf)
        float wa  = __expf(sa - nm);
        float wb  = __expf(sb - nm);
        l = fmaf(l, scl, wa + wb);
        acc.x = fmaf(wb, xb.x, fmaf(wa, xa.x, acc.x * scl));
        acc.y = fmaf(wb, xb.y, fmaf(wa, xa.y, acc.y * scl));
        m = nm;
    }
    if (idx < end) {                                  // odd tail, data in x0
        float2 xa = x0;
        float2 pa;
        pa.x = xa.x + xr_v.x; pa.y = xa.y + xr_v.y;
        pa.x = fmaxf(pa.x, SLOPE * pa.x); pa.y = fmaxf(pa.y, SLOPE * pa.y);
        float sa = fmaf(pa.x, a2.x, pa.y * a2.y);
        sa += __shfl_xor(sa, 1);
        sa += __shfl_xor(sa, 2);
        sa += __shfl_xor(sa, 4);
        sa += __shfl_xor(sa, 8);
        float nm = fmaxf(m, sa);
        float scl = __expf(m - nm);
        float wa  = __expf(sa - nm);
        l = fmaf(l, scl, wa);
        acc.x = fmaf(wa, xa.x, acc.x * scl);
        acc.y = fmaf(wa, xa.y, acc.y * scl);
    }
    float rl = 1.f / l;
    int o = v * 64 + lane;
    float2 yv = ((const float2*)y)[o];
    yv.x = fmaf(acc.x, rl, yv.x);                     // agg + res(+bias)
    yv.y = fmaf(acc.y, rl, yv.y);
    ((float2*)y)[o] = yv;
}

// ---------- BatchNorm stats ----------
__global__ __launch_bounds__(128) void bn_stats_kernel(const float* __restrict__ y,
                                                       float* __restrict__ sums) {
    int t = threadIdx.x;
    float s = 0.f, s2 = 0.f;
    for (int r = blockIdx.x; r < N; r += gridDim.x) {
        float v = y[r * D + t];
        s += v;
        s2 = fmaf(v, v, s2);
    }
    atomicAdd(&sums[t], s);
    atomicAdd(&sums[D + t], s2);
}

__global__ __launch_bounds__(128) void bn_finalize_kernel(const float* __restrict__ sums,
                                                          const float* __restrict__ gamma,
                                                          const float* __restrict__ beta,
                                                          float* __restrict__ ss) {
    int t = threadIdx.x;
    float mean = sums[t] * (1.0f / N);
    float var = sums[D + t] * (1.0f / N) - mean * mean;
    var = fmaxf(var, 0.f);
    float sc = gamma[t] * rsqrtf(var + BN_EPS);
    ss[t] = sc;
    ss[D + t] = beta[t] - mean * sc;
}

extern "C" void kernel_launch(void* const* d_in, const int* in_sizes, int n_in,
                              void* d_out, int out_size, void* d_ws, size_t ws_size,
                              hipStream_t stream) {
    const float* x_in  = (const float*)d_in[0];
    const int*   ei    = (const int*)d_in[1];
    const float* Wl    = (const float*)d_in[2];
    const float* Wr    = (const float*)d_in[3];
    const float* att   = (const float*)d_in[4];
    const float* bias  = (const float*)d_in[5];
    const float* Wres  = (const float*)d_in[6];
    const float* gamma = (const float*)d_in[7];
    const float* beta  = (const float*)d_in[8];
    const float* Wout  = (const float*)d_in[9];
    const float* bout  = (const float*)d_in[10];
    float* out = (float*)d_out;

    char* ws = (char*)d_ws;
    size_t off = 0;
    auto alloc = [&](size_t bytes) {
        void* p = ws + off;
        off = (off + bytes + 255) & ~(size_t)255;
        return p;
    };
    float* xl       = (float*)alloc((size_t)N * D * sizeof(float));
    float* xr       = (float*)alloc((size_t)N * D * sizeof(float));
    float* y        = (float*)alloc((size_t)N * D * sizeof(float));
    hbf*   xh       = (hbf*)alloc((size_t)NPAD * D * sizeof(hbf));
    hbf*   xlo      = (hbf*)alloc((size_t)NPAD * D * sizeof(hbf));
    hbf*   Wph      = (hbf*)alloc((size_t)10 * D * D * sizeof(hbf));
    hbf*   Wpl      = (hbf*)alloc((size_t)10 * D * D * sizeof(hbf));
    int*   row_ptr  = (int*)alloc((size_t)(N + 1) * sizeof(int));
    int*   col_idx  = (int*)alloc((size_t)E2 * sizeof(int));
    int*   counts   = (int*)alloc((size_t)N * sizeof(int));   // reused as write ptr
    int*   blk_sums = (int*)alloc(128 * sizeof(int));
    float* sums     = (float*)alloc(2 * D * sizeof(float));
    float* ss       = (float*)alloc(2 * D * sizeof(float));

    const int NB = (N + 511) / 512;                  // 98 scan blocks
    const int GB = NPAD / 64;                        // 782 gemm blocks

    // CSR build + weight packing
    hipMemsetAsync(counts, 0, (size_t)N * sizeof(int), stream);
    count_kernel<<<(E2 + 255) / 256, 256, 0, stream>>>(ei, counts);
    pack_w_kernel<<<10 * 16384 / 256, 256, 0, stream>>>(Wl, Wr, Wres, Wout, Wph, Wpl);
    scan_block_kernel<<<NB, 512, 0, stream>>>(counts, row_ptr, blk_sums);
    scan_sums_kernel<<<1, 128, 0, stream>>>(blk_sums, NB);
    scan_add_kernel<<<(N + 255) / 256, 256, 0, stream>>>(row_ptr, blk_sums);
    hipMemsetAsync(counts, 0, (size_t)N * sizeof(int), stream);
    scatter_kernel<<<(E2 + 255) / 256, 256, 0, stream>>>(ei, row_ptr, counts, col_idx);

    for (int i = 0; i < L; ++i) {
        const float* xin = (i == 0) ? x_in : y;
        const float* ssi = (i == 0) ? nullptr : ss;  // BN(i-1)+leaky fused into prep
        prep_x_kernel<<<(NPAD * D + 255) / 256, 256, 0, stream>>>(xin, ssi, xh, xlo);
        gemm3_mfma_kernel<<<GB, 256, 0, stream>>>(xh, xlo, Wph, Wpl, i, 3 + i, 6 + i,
                                                  bias + (size_t)i * D, xl, xr, y);
        gat_kernel<<<N / 2, 128, 0, stream>>>(xl, xr, y, row_ptr, col_idx,
                                              att + (size_t)i * H * C);
        hipMemsetAsync(sums, 0, 2 * D * sizeof(float), stream);
        bn_stats_kernel<<<256, 128, 0, stream>>>(y, sums);
        bn_finalize_kernel<<<1, 128, 0, stream>>>(sums, gamma + (size_t)i * D,
                                                  beta + (size_t)i * D, ss);
    }

    prep_x_kernel<<<(NPAD * D + 255) / 256, 256, 0, stream>>>(y, ss, xh, xlo);
    gemm_out_mfma_kernel<<<GB, 256, 0, stream>>>(xh, xlo, Wph, Wpl, bout, out);
}

// Round 6
// 857.319 us; speedup vs baseline: 1.2038x; 1.0741x over previous
//
#include <hip/hip_runtime.h>
#include <hip/hip_bf16.h>

constexpr int N = 50000;
constexpr int E = 800000;
constexpr int D = 128;
constexpr int H = 4;
constexpr int C = 32;
constexpr int L = 3;
constexpr int E2 = E + N;           // edges + self loops
constexpr float SLOPE = 0.2f;
constexpr float BN_EPS = 1e-5f;

typedef __attribute__((ext_vector_type(8))) short bf16x8_t;   // 8 bf16 (4 VGPRs)
typedef __attribute__((ext_vector_type(4))) float f32x4_t;    // MFMA C/D

using hbf = __hip_bfloat16;

__device__ __forceinline__ short f2bf(float v) {
    hbf h = __float2bfloat16(v);
    return *reinterpret_cast<short*>(&h);
}
__device__ __forceinline__ float2 bfpair_to_f2(unsigned int u) {
    float2 r;
    r.x = __uint_as_float(u << 16);
    r.y = __uint_as_float(u & 0xffff0000u);
    return r;
}

// ---------- CSR build ----------
__global__ void count_kernel(const int* __restrict__ ei, int* __restrict__ counts) {
    int i = blockIdx.x * blockDim.x + threadIdx.x;
    if (i >= E2) return;
    int dst = (i < E) ? ei[E + i] : (i - E);
    atomicAdd(&counts[dst], 1);
}

__global__ __launch_bounds__(512) void scan_block_kernel(const int* __restrict__ counts,
                                                         int* __restrict__ row_ptr,
                                                         int* __restrict__ blk_sums) {
    __shared__ int s[512];
    int t = threadIdx.x;
    int i = blockIdx.x * 512 + t;
    int v = (i < N) ? counts[i] : 0;
    s[t] = v;
    __syncthreads();
    for (int off = 1; off < 512; off <<= 1) {
        int add = (t >= off) ? s[t - off] : 0;
        __syncthreads();
        s[t] += add;
        __syncthreads();
    }
    if (i < N) row_ptr[i] = s[t] - v;                 // exclusive within block
    if (t == 511) blk_sums[blockIdx.x] = s[511];
}

__global__ __launch_bounds__(128) void scan_sums_kernel(int* __restrict__ blk, int nb) {
    __shared__ int s[128];
    int t = threadIdx.x;
    int v = (t < nb) ? blk[t] : 0;
    s[t] = v;
    __syncthreads();
    for (int off = 1; off < 128; off <<= 1) {
        int add = (t >= off) ? s[t - off] : 0;
        __syncthreads();
        s[t] += add;
        __syncthreads();
    }
    if (t < nb) blk[t] = s[t] - v;                    // exclusive block offsets
}

__global__ void scan_add_kernel(int* __restrict__ row_ptr, const int* __restrict__ blk) {
    int i = blockIdx.x * blockDim.x + threadIdx.x;
    if (i < N) row_ptr[i] += blk[i >> 9];
    if (i == 0) row_ptr[N] = E2;
}

__global__ void scatter_kernel(const int* __restrict__ ei, const int* __restrict__ row_ptr,
                               int* __restrict__ wp, int* __restrict__ col_idx) {
    int i = blockIdx.x * blockDim.x + threadIdx.x;
    if (i >= E2) return;
    int src, dst;
    if (i < E) { src = ei[i]; dst = ei[E + i]; }
    else       { src = i - E; dst = i - E; }
    int pos = row_ptr[dst] + atomicAdd(&wp[dst], 1);
    col_idx[pos] = src;
}

// ---------- pack all 10 weight matrices into MFMA B-fragment order, hi/lo bf16 ----------
// B frag for 16x16x32: lane holds B[k = ks*32 + (lane>>4)*8 + j][n = nb*16 + (lane&15)],
// j=0..7. Packed index: (mat*2048 + (ks*8+nb)*64 + lane)*8 + j  -> lane-contiguous 16B.
__global__ __launch_bounds__(256) void pack_w_kernel(
        const float* __restrict__ Wl, const float* __restrict__ Wr,
        const float* __restrict__ Wres, const float* __restrict__ Wout,
        hbf* __restrict__ Wph, hbf* __restrict__ Wpl) {
    int gid = blockIdx.x * 256 + threadIdx.x;        // 10 * 16384
    int mat = gid >> 14;
    int d = gid & 16383;
    const float* W;
    if (mat < 3)      W = Wl + (size_t)mat * 16384;
    else if (mat < 6) W = Wr + (size_t)(mat - 3) * 16384;
    else if (mat < 9) W = Wres + (size_t)(mat - 6) * 16384;
    else              W = Wout;
    int j = d & 7, lane = (d >> 3) & 63, nb = (d >> 9) & 7, ks = d >> 12;
    int k = ks * 32 + ((lane >> 4) * 8) + j;
    int n = nb * 16 + (lane & 15);
    float w = W[k * D + n];
    hbf hi = __float2bfloat16(w);
    hbf lo = __float2bfloat16(w - __bfloat162float(hi));
    Wph[gid] = hi;
    Wpl[gid] = lo;
}

// ---------- fused 3-matrix MFMA GEMM, self-staging ----------
// X = leaky(bn(x)) if ss else x (64-row tile staged in LDS, fp32).
// xl = bf16(X@Wl), xr = X@Wr, y = X@Wres + bias.  May run in-place (x == y).
__global__ __launch_bounds__(256) void gemm3_mfma_kernel(
        const float* x, const float* __restrict__ ss,
        const hbf* __restrict__ Wph, const hbf* __restrict__ Wpl,
        int mL, int mR, int mS, const float* __restrict__ bias,
        hbf* __restrict__ xl, float* __restrict__ xr, float* y) {
    __shared__ float xs[64][133];                     // +5 pad: 2-way max bank aliasing
    int t = threadIdx.x;
    int row0 = blockIdx.x * 64;
    {
        const float4* x4 = (const float4*)(x + (size_t)row0 * D);
        int cg = (t & 31) * 4;                        // fixed col group per thread
        float4 sc4 = make_float4(1.f, 1.f, 1.f, 1.f);
        float4 sh4 = make_float4(0.f, 0.f, 0.f, 0.f);
        if (ss) {
            sc4 = *(const float4*)(ss + cg);
            sh4 = *(const float4*)(ss + D + cg);
        }
        for (int i = t; i < 64 * 32; i += 256) {
            int r = i >> 5;
            float4 v = make_float4(0.f, 0.f, 0.f, 0.f);
            if (row0 + r < N) {
                v = x4[i];
                if (ss) {
                    v.x = fmaf(v.x, sc4.x, sh4.x); v.x = fmaxf(v.x, SLOPE * v.x);
                    v.y = fmaf(v.y, sc4.y, sh4.y); v.y = fmaxf(v.y, SLOPE * v.y);
                    v.z = fmaf(v.z, sc4.z, sh4.z); v.z = fmaxf(v.z, SLOPE * v.z);
                    v.w = fmaf(v.w, sc4.w, sh4.w); v.w = fmaxf(v.w, SLOPE * v.w);
                }
            }
            *(float4*)&xs[r][cg] = v;
        }
    }
    __syncthreads();

    int wave = t >> 6;
    int lane = t & 63;
    int mrow = wave * 16 + (lane & 15);
    int koff = (lane >> 4) * 8;
    const bf16x8_t* BH = (const bf16x8_t*)Wph;
    const bf16x8_t* BL = (const bf16x8_t*)Wpl;

    f32x4_t aL[8], aR[8], aS[8];
#pragma unroll
    for (int nb = 0; nb < 8; ++nb) {
        aL[nb] = (f32x4_t)0.f; aR[nb] = (f32x4_t)0.f; aS[nb] = (f32x4_t)0.f;
    }
    for (int ks = 0; ks < 4; ++ks) {
        const float* src = &xs[mrow][ks * 32 + koff];
        float4 f0 = *(const float4*)src;
        float4 f1 = *(const float4*)(src + 4);
        float f[8] = {f0.x, f0.y, f0.z, f0.w, f1.x, f1.y, f1.z, f1.w};
        bf16x8_t ah, al;
#pragma unroll
        for (int j = 0; j < 8; ++j) {
            short hi = f2bf(f[j]);
            unsigned int hu = ((unsigned int)(unsigned short)hi) << 16;
            float lo = f[j] - __uint_as_float(hu);
            ah[j] = hi;
            al[j] = f2bf(lo);
        }
#pragma unroll
        for (int nb = 0; nb < 8; ++nb) {
            int bidx = (ks * 8 + nb) * 64 + lane;
            bf16x8_t bh, bl;
            bh = BH[mL * 2048 + bidx]; bl = BL[mL * 2048 + bidx];
            aL[nb] = __builtin_amdgcn_mfma_f32_16x16x32_bf16(ah, bh, aL[nb], 0, 0, 0);
            aL[nb] = __builtin_amdgcn_mfma_f32_16x16x32_bf16(al, bh, aL[nb], 0, 0, 0);
            aL[nb] = __builtin_amdgcn_mfma_f32_16x16x32_bf16(ah, bl, aL[nb], 0, 0, 0);
            bh = BH[mR * 2048 + bidx]; bl = BL[mR * 2048 + bidx];
            aR[nb] = __builtin_amdgcn_mfma_f32_16x16x32_bf16(ah, bh, aR[nb], 0, 0, 0);
            aR[nb] = __builtin_amdgcn_mfma_f32_16x16x32_bf16(al, bh, aR[nb], 0, 0, 0);
            aR[nb] = __builtin_amdgcn_mfma_f32_16x16x32_bf16(ah, bl, aR[nb], 0, 0, 0);
            bh = BH[mS * 2048 + bidx]; bl = BL[mS * 2048 + bidx];
            aS[nb] = __builtin_amdgcn_mfma_f32_16x16x32_bf16(ah, bh, aS[nb], 0, 0, 0);
            aS[nb] = __builtin_amdgcn_mfma_f32_16x16x32_bf16(al, bh, aS[nb], 0, 0, 0);
            aS[nb] = __builtin_amdgcn_mfma_f32_16x16x32_bf16(ah, bl, aS[nb], 0, 0, 0);
        }
    }
    // C/D layout: col = lane&15, row = (lane>>4)*4 + r
    int col = lane & 15;
    int rowq = row0 + wave * 16 + (lane >> 4) * 4;
#pragma unroll
    for (int nb = 0; nb < 8; ++nb) {
        int n = nb * 16 + col;
        float bv = bias[n];
#pragma unroll
        for (int r = 0; r < 4; ++r) {
            int row = rowq + r;
            if (row < N) {
                xl[(size_t)row * D + n] = __float2bfloat16(aL[nb][r]);
                xr[(size_t)row * D + n] = aR[nb][r];
                y[(size_t)row * D + n]  = aS[nb][r] + bv;
            }
        }
    }
}

// ---------- final linear via MFMA, self-staging (BN+leaky on load) ----------
__global__ __launch_bounds__(256) void gemm_out_mfma_kernel(
        const float* __restrict__ x, const float* __restrict__ ss,
        const hbf* __restrict__ Wph, const hbf* __restrict__ Wpl,
        const float* __restrict__ b, float* __restrict__ out) {
    __shared__ float xs[64][133];
    int t = threadIdx.x;
    int row0 = blockIdx.x * 64;
    {
        const float4* x4 = (const float4*)(x + (size_t)row0 * D);
        int cg = (t & 31) * 4;
        float4 sc4 = *(const float4*)(ss + cg);
        float4 sh4 = *(const float4*)(ss + D + cg);
        for (int i = t; i < 64 * 32; i += 256) {
            int r = i >> 5;
            float4 v = make_float4(0.f, 0.f, 0.f, 0.f);
            if (row0 + r < N) {
                v = x4[i];
                v.x = fmaf(v.x, sc4.x, sh4.x); v.x = fmaxf(v.x, SLOPE * v.x);
                v.y = fmaf(v.y, sc4.y, sh4.y); v.y = fmaxf(v.y, SLOPE * v.y);
                v.z = fmaf(v.z, sc4.z, sh4.z); v.z = fmaxf(v.z, SLOPE * v.z);
                v.w = fmaf(v.w, sc4.w, sh4.w); v.w = fmaxf(v.w, SLOPE * v.w);
            }
            *(float4*)&xs[r][cg] = v;
        }
    }
    __syncthreads();

    int wave = t >> 6;
    int lane = t & 63;
    int mrow = wave * 16 + (lane & 15);
    int koff = (lane >> 4) * 8;
    const bf16x8_t* BH = (const bf16x8_t*)Wph + 9 * 2048;   // matrix 9 = Wout
    const bf16x8_t* BL = (const bf16x8_t*)Wpl + 9 * 2048;

    f32x4_t acc[8];
#pragma unroll
    for (int nb = 0; nb < 8; ++nb) acc[nb] = (f32x4_t)0.f;
    for (int ks = 0; ks < 4; ++ks) {
        const float* src = &xs[mrow][ks * 32 + koff];
        float4 f0 = *(const float4*)src;
        float4 f1 = *(const float4*)(src + 4);
        float f[8] = {f0.x, f0.y, f0.z, f0.w, f1.x, f1.y, f1.z, f1.w};
        bf16x8_t ah, al;
#pragma unroll
        for (int j = 0; j < 8; ++j) {
            short hi = f2bf(f[j]);
            unsigned int hu = ((unsigned int)(unsigned short)hi) << 16;
            float lo = f[j] - __uint_as_float(hu);
            ah[j] = hi;
            al[j] = f2bf(lo);
        }
#pragma unroll
        for (int nb = 0; nb < 8; ++nb) {
            int bidx = (ks * 8 + nb) * 64 + lane;
            bf16x8_t bh = BH[bidx], bl = BL[bidx];
            acc[nb] = __builtin_amdgcn_mfma_f32_16x16x32_bf16(ah, bh, acc[nb], 0, 0, 0);
            acc[nb] = __builtin_amdgcn_mfma_f32_16x16x32_bf16(al, bh, acc[nb], 0, 0, 0);
            acc[nb] = __builtin_amdgcn_mfma_f32_16x16x32_bf16(ah, bl, acc[nb], 0, 0, 0);
        }
    }
    int col = lane & 15;
    int rowq = row0 + wave * 16 + (lane >> 4) * 4;
#pragma unroll
    for (int nb = 0; nb < 8; ++nb) {
        int n = nb * 16 + col;
        float bv = b[n];
#pragma unroll
        for (int r = 0; r < 4; ++r) {
            int row = rowq + r;
            if (row < N) out[(size_t)row * D + n] = acc[nb][r] + bv;
        }
    }
}

// ---------- GATv2 aggregation, one wave per node, bf16 xl gather, 2-edge unroll ----------
__global__ __launch_bounds__(128) void gat_kernel(
        const hbf* __restrict__ xl, const float* __restrict__ xr,
        float* y, const int* __restrict__ row_ptr,
        const int* __restrict__ col_idx, const float* __restrict__ att) {
    int wave = threadIdx.x >> 6;
    int lane = threadIdx.x & 63;
    int v = blockIdx.x * 2 + wave;
    const unsigned int* xlp = (const unsigned int*)xl;        // bf16 pair per lane
    float2 xr_v = ((const float2*)xr)[v * 64 + lane];
    float2 a2 = ((const float2*)att)[lane];           // channels 2l,2l+1; head = lane/16
    int beg = row_ptr[v], end = row_ptr[v + 1];
    float m = -INFINITY, l = 0.f;
    float2 acc = make_float2(0.f, 0.f);
    unsigned int u0 = xlp[(size_t)col_idx[beg] * 64 + lane];  // degree >= 1
    unsigned int u1 = 0;
    if (beg + 1 < end) u1 = xlp[(size_t)col_idx[beg + 1] * 64 + lane];
    int idx = beg;
    for (; idx + 1 < end; idx += 2) {
        float2 xa = bfpair_to_f2(u0);
        float2 xb = bfpair_to_f2(u1);
        if (idx + 2 < end) u0 = xlp[(size_t)col_idx[idx + 2] * 64 + lane];
        if (idx + 3 < end) u1 = xlp[(size_t)col_idx[idx + 3] * 64 + lane];
        float2 pa, pb;
        pa.x = xa.x + xr_v.x; pa.y = xa.y + xr_v.y;
        pb.x = xb.x + xr_v.x; pb.y = xb.y + xr_v.y;
        pa.x = fmaxf(pa.x, SLOPE * pa.x); pa.y = fmaxf(pa.y, SLOPE * pa.y);
        pb.x = fmaxf(pb.x, SLOPE * pb.x); pb.y = fmaxf(pb.y, SLOPE * pb.y);
        float sa = fmaf(pa.x, a2.x, pa.y * a2.y);
        float sb = fmaf(pb.x, a2.x, pb.y * a2.y);
        sa += __shfl_xor(sa, 1);  sb += __shfl_xor(sb, 1);
        sa += __shfl_xor(sa, 2);  sb += __shfl_xor(sb, 2);
        sa += __shfl_xor(sa, 4);  sb += __shfl_xor(sb, 4);
        sa += __shfl_xor(sa, 8);  sb += __shfl_xor(sb, 8);
        float nm = fmaxf(m, fmaxf(sa, sb));
        float scl = __expf(m - nm);                   // 0 on first iter (m=-inf)
        float wa  = __expf(sa - nm);
        float wb  = __expf(sb - nm);
        l = fmaf(l, scl, wa + wb);
        acc.x = fmaf(wb, xb.x, fmaf(wa, xa.x, acc.x * scl));
        acc.y = fmaf(wb, xb.y, fmaf(wa, xa.y, acc.y * scl));
        m = nm;
    }
    if (idx < end) {                                  // odd tail, data in u0
        float2 xa = bfpair_to_f2(u0);
        float2 pa;
        pa.x = xa.x + xr_v.x; pa.y = xa.y + xr_v.y;
        pa.x = fmaxf(pa.x, SLOPE * pa.x); pa.y = fmaxf(pa.y, SLOPE * pa.y);
        float sa = fmaf(pa.x, a2.x, pa.y * a2.y);
        sa += __shfl_xor(sa, 1);
        sa += __shfl_xor(sa, 2);
        sa += __shfl_xor(sa, 4);
        sa += __shfl_xor(sa, 8);
        float nm = fmaxf(m, sa);
        float scl = __expf(m - nm);
        float wa  = __expf(sa - nm);
        l = fmaf(l, scl, wa);
        acc.x = fmaf(wa, xa.x, acc.x * scl);
        acc.y = fmaf(wa, xa.y, acc.y * scl);
    }
    float rl = 1.f / l;
    int o = v * 64 + lane;
    float2 yv = ((const float2*)y)[o];
    yv.x = fmaf(acc.x, rl, yv.x);                     // agg + res(+bias)
    yv.y = fmaf(acc.y, rl, yv.y);
    ((float2*)y)[o] = yv;
}

// ---------- BatchNorm stats: coalesced float4, LDS reduce, atomics ----------
__global__ __launch_bounds__(256) void bn_stats_kernel(const float* __restrict__ y,
                                                       float* __restrict__ sums) {
    __shared__ float ls[256][4];
    __shared__ float ls2[256][4];
    int t = threadIdx.x;
    float4 s = make_float4(0.f, 0.f, 0.f, 0.f);
    float4 s2 = make_float4(0.f, 0.f, 0.f, 0.f);
    const float4* y4 = (const float4*)y;
    for (int i = blockIdx.x * 256 + t; i < N * D / 4; i += gridDim.x * 256) {
        float4 v = y4[i];                             // cols 4*(t&31)..+3 (fixed)
        s.x += v.x; s.y += v.y; s.z += v.z; s.w += v.w;
        s2.x = fmaf(v.x, v.x, s2.x); s2.y = fmaf(v.y, v.y, s2.y);
        s2.z = fmaf(v.z, v.z, s2.z); s2.w = fmaf(v.w, v.w, s2.w);
    }
    ls[t][0] = s.x;  ls[t][1] = s.y;  ls[t][2] = s.z;  ls[t][3] = s.w;
    ls2[t][0] = s2.x; ls2[t][1] = s2.y; ls2[t][2] = s2.z; ls2[t][3] = s2.w;
    __syncthreads();
    if (t < D) {
        int g = t >> 2, e = t & 3;
        float a = 0.f, b = 0.f;
#pragma unroll
        for (int j = 0; j < 8; ++j) {
            a += ls[g + 32 * j][e];
            b += ls2[g + 32 * j][e];
        }
        atomicAdd(&sums[t], a);
        atomicAdd(&sums[D + t], b);
    }
}

__global__ __launch_bounds__(128) void bn_finalize_kernel(const float* __restrict__ sums,
                                                          const float* __restrict__ gamma,
                                                          const float* __restrict__ beta,
                                                          float* __restrict__ ss) {
    int t = threadIdx.x;
    float mean = sums[t] * (1.0f / N);
    float var = sums[D + t] * (1.0f / N) - mean * mean;
    var = fmaxf(var, 0.f);
    float sc = gamma[t] * rsqrtf(var + BN_EPS);
    ss[t] = sc;
    ss[D + t] = beta[t] - mean * sc;
}

extern "C" void kernel_launch(void* const* d_in, const int* in_sizes, int n_in,
                              void* d_out, int out_size, void* d_ws, size_t ws_size,
                              hipStream_t stream) {
    const float* x_in  = (const float*)d_in[0];
    const int*   ei    = (const int*)d_in[1];
    const float* Wl    = (const float*)d_in[2];
    const float* Wr    = (const float*)d_in[3];
    const float* att   = (const float*)d_in[4];
    const float* bias  = (const float*)d_in[5];
    const float* Wres  = (const float*)d_in[6];
    const float* gamma = (const float*)d_in[7];
    const float* beta  = (const float*)d_in[8];
    const float* Wout  = (const float*)d_in[9];
    const float* bout  = (const float*)d_in[10];
    float* out = (float*)d_out;

    char* ws = (char*)d_ws;
    size_t off = 0;
    auto alloc = [&](size_t bytes) {
        void* p = ws + off;
        off = (off + bytes + 255) & ~(size_t)255;
        return p;
    };
    hbf*   xl       = (hbf*)alloc((size_t)N * D * sizeof(hbf));
    float* xr       = (float*)alloc((size_t)N * D * sizeof(float));
    float* y        = (float*)alloc((size_t)N * D * sizeof(float));
    hbf*   Wph      = (hbf*)alloc((size_t)10 * D * D * sizeof(hbf));
    hbf*   Wpl      = (hbf*)alloc((size_t)10 * D * D * sizeof(hbf));
    int*   row_ptr  = (int*)alloc((size_t)(N + 1) * sizeof(int));
    int*   col_idx  = (int*)alloc((size_t)E2 * sizeof(int));
    int*   counts   = (int*)alloc((size_t)N * sizeof(int));   // reused as write ptr
    int*   blk_sums = (int*)alloc(128 * sizeof(int));
    float* sums     = (float*)alloc(2 * D * sizeof(float));
    float* ss       = (float*)alloc(2 * D * sizeof(float));

    const int NB = (N + 511) / 512;                  // 98 scan blocks
    const int GB = (N + 63) / 64;                    // 782 gemm blocks

    // CSR build + weight packing
    hipMemsetAsync(counts, 0, (size_t)N * sizeof(int), stream);
    count_kernel<<<(E2 + 255) / 256, 256, 0, stream>>>(ei, counts);
    pack_w_kernel<<<10 * 16384 / 256, 256, 0, stream>>>(Wl, Wr, Wres, Wout, Wph, Wpl);
    scan_block_kernel<<<NB, 512, 0, stream>>>(counts, row_ptr, blk_sums);
    scan_sums_kernel<<<1, 128, 0, stream>>>(blk_sums, NB);
    scan_add_kernel<<<(N + 255) / 256, 256, 0, stream>>>(row_ptr, blk_sums);
    hipMemsetAsync(counts, 0, (size_t)N * sizeof(int), stream);
    scatter_kernel<<<(E2 + 255) / 256, 256, 0, stream>>>(ei, row_ptr, counts, col_idx);

    for (int i = 0; i < L; ++i) {
        const float* xin = (i == 0) ? x_in : y;      // in-place (own rows only) for 1,2
        const float* ssi = (i == 0) ? nullptr : ss;  // BN(i-1)+leaky fused into staging
        gemm3_mfma_kernel<<<GB, 256, 0, stream>>>(xin, ssi, Wph, Wpl, i, 3 + i, 6 + i,
                                                  bias + (size_t)i * D, xl, xr, y);
        gat_kernel<<<N / 2, 128, 0, stream>>>(xl, xr, y, row_ptr, col_idx,
                                              att + (size_t)i * H * C);
        hipMemsetAsync(sums, 0, 2 * D * sizeof(float), stream);
        bn_stats_kernel<<<1024, 256, 0, stream>>>(y, sums);
        bn_finalize_kernel<<<1, 128, 0, stream>>>(sums, gamma + (size_t)i * D,
                                                  beta + (size_t)i * D, ss);
    }

    gemm_out_mfma_kernel<<<GB, 256, 0, stream>>>(y, ss, Wph, Wpl, bout, out);
}

// Round 7
// 684.844 us; speedup vs baseline: 1.5069x; 1.2518x over previous
//
#include <hip/hip_runtime.h>
#include <hip/hip_bf16.h>

constexpr int N = 50000;
constexpr int E = 800000;
constexpr int D = 128;
constexpr int H = 4;
constexpr int C = 32;
constexpr int L = 3;
constexpr int E2 = E + N;           // edges + self loops
constexpr float SLOPE = 0.2f;
constexpr float BN_EPS = 1e-5f;
constexpr int TILES = (N + 63) / 64;                 // 782 row tiles

typedef __attribute__((ext_vector_type(8))) short bf16x8_t;   // 8 bf16 (4 VGPRs)
typedef __attribute__((ext_vector_type(4))) float f32x4_t;    // MFMA C/D

using hbf = __hip_bfloat16;

__device__ __forceinline__ short f2bf(float v) {
    hbf h = __float2bfloat16(v);
    return *reinterpret_cast<short*>(&h);
}
__device__ __forceinline__ float2 bfpair_to_f2(unsigned int u) {
    float2 r;
    r.x = __uint_as_float(u << 16);
    r.y = __uint_as_float(u & 0xffff0000u);
    return r;
}

// ---------- CSR build ----------
__global__ void count_kernel(const int* __restrict__ ei, int* __restrict__ counts) {
    int i = blockIdx.x * blockDim.x + threadIdx.x;
    if (i >= E2) return;
    int dst = (i < E) ? ei[E + i] : (i - E);
    atomicAdd(&counts[dst], 1);
}

__global__ __launch_bounds__(512) void scan_block_kernel(const int* __restrict__ counts,
                                                         int* __restrict__ row_ptr,
                                                         int* __restrict__ blk_sums) {
    __shared__ int s[512];
    int t = threadIdx.x;
    int i = blockIdx.x * 512 + t;
    int v = (i < N) ? counts[i] : 0;
    s[t] = v;
    __syncthreads();
    for (int off = 1; off < 512; off <<= 1) {
        int add = (t >= off) ? s[t - off] : 0;
        __syncthreads();
        s[t] += add;
        __syncthreads();
    }
    if (i < N) row_ptr[i] = s[t] - v;                 // exclusive within block
    if (t == 511) blk_sums[blockIdx.x] = s[511];
}

__global__ __launch_bounds__(128) void scan_sums_kernel(int* __restrict__ blk, int nb) {
    __shared__ int s[128];
    int t = threadIdx.x;
    int v = (t < nb) ? blk[t] : 0;
    s[t] = v;
    __syncthreads();
    for (int off = 1; off < 128; off <<= 1) {
        int add = (t >= off) ? s[t - off] : 0;
        __syncthreads();
        s[t] += add;
        __syncthreads();
    }
    if (t < nb) blk[t] = s[t] - v;                    // exclusive block offsets
}

__global__ void scan_add_kernel(int* __restrict__ row_ptr, const int* __restrict__ blk) {
    int i = blockIdx.x * blockDim.x + threadIdx.x;
    if (i < N) row_ptr[i] += blk[i >> 9];
    if (i == 0) row_ptr[N] = E2;
}

__global__ void scatter_kernel(const int* __restrict__ ei, const int* __restrict__ row_ptr,
                               int* __restrict__ wp, int* __restrict__ col_idx) {
    int i = blockIdx.x * blockDim.x + threadIdx.x;
    if (i >= E2) return;
    int src, dst;
    if (i < E) { src = ei[i]; dst = ei[E + i]; }
    else       { src = i - E; dst = i - E; }
    int pos = row_ptr[dst] + atomicAdd(&wp[dst], 1);
    col_idx[pos] = src;
}

// ---------- pack 10 weight matrices into MFMA B-fragment order (hi bf16 only) ----------
// B frag for 16x16x32: lane holds B[k = ks*32 + (lane>>4)*8 + j][n = nb*16 + (lane&15)],
// j=0..7. Packed index: (mat*2048 + (ks*8+nb)*64 + lane)*8 + j  -> lane-contiguous 16B.
__global__ __launch_bounds__(256) void pack_w_kernel(
        const float* __restrict__ Wl, const float* __restrict__ Wr,
        const float* __restrict__ Wres, const float* __restrict__ Wout,
        hbf* __restrict__ Wph) {
    int gid = blockIdx.x * 256 + threadIdx.x;        // 10 * 16384
    int mat = gid >> 14;
    int d = gid & 16383;
    const float* W;
    if (mat < 3)      W = Wl + (size_t)mat * 16384;
    else if (mat < 6) W = Wr + (size_t)(mat - 3) * 16384;
    else if (mat < 9) W = Wres + (size_t)(mat - 6) * 16384;
    else              W = Wout;
    int j = d & 7, lane = (d >> 3) & 63, nb = (d >> 9) & 7, ks = d >> 12;
    int k = ks * 32 + ((lane >> 4) * 8) + j;
    int n = nb * 16 + (lane & 15);
    Wph[gid] = __float2bfloat16(W[k * D + n]);
}

// ---------- fused 3-matrix MFMA GEMM, persistent grid-stride over row tiles ----------
// X = leaky(bn(x)) if ss else x (64-row tile staged in LDS fp32).
// xl = bf16(X@Wl), xr = X@Wr, y = X@Wres + bias.  May run in-place (x == y): the
// tile is snapshot into LDS before any store, and each tile is owned by one block.
// Wave w owns n-blocks {2w, 2w+1}; B frags (3 mats x 4 ks x 2 nb = 24) live in VGPRs,
// loaded ONCE per block (fixes r6's 104us L2-latency stall: MfmaUtil 5%, both pipes idle).
// 2-term split: X@W ~= Xh@Wh + Xl@Wh (W bf16-rounded, err ~2^-9|W|).
__global__ __launch_bounds__(256) void gemm3_mfma_kernel(
        const float* x, const float* __restrict__ ss,
        const hbf* __restrict__ Wph,
        int mL, int mR, int mS, const float* __restrict__ bias,
        hbf* __restrict__ xl, float* __restrict__ xr, float* y) {
    __shared__ float xs[64][133];                     // +5 pad: 2-way max bank aliasing
    int t = threadIdx.x;
    int wave = t >> 6;
    int lane = t & 63;
    int nb0 = wave * 2;                               // this wave's two n-blocks

    const bf16x8_t* B = (const bf16x8_t*)Wph;
    bf16x8_t bL[4][2], bR[4][2], bS[4][2];            // 24 frags = 96 VGPRs, loaded once
#pragma unroll
    for (int ks = 0; ks < 4; ++ks)
#pragma unroll
        for (int j = 0; j < 2; ++j) {
            int bo = (ks * 8 + nb0 + j) * 64 + lane;
            bL[ks][j] = B[mL * 2048 + bo];
            bR[ks][j] = B[mR * 2048 + bo];
            bS[ks][j] = B[mS * 2048 + bo];
        }

    int cg = (t & 31) * 4;                            // staging col group
    float4 sc4 = make_float4(1.f, 1.f, 1.f, 1.f);
    float4 sh4 = make_float4(0.f, 0.f, 0.f, 0.f);
    if (ss) {
        sc4 = *(const float4*)(ss + cg);
        sh4 = *(const float4*)(ss + D + cg);
    }
    int col = lane & 15;
    int koff = (lane >> 4) * 8;

    for (int tt = blockIdx.x; tt < TILES; tt += gridDim.x) {
        int row0 = tt * 64;
        __syncthreads();                              // prev tile's LDS reads done
        {
            const float4* x4 = (const float4*)(x + (size_t)row0 * D);
            for (int i = t; i < 64 * 32; i += 256) {
                int r = i >> 5;
                float4 v = make_float4(0.f, 0.f, 0.f, 0.f);
                if (row0 + r < N) {
                    v = x4[i];
                    if (ss) {
                        v.x = fmaf(v.x, sc4.x, sh4.x); v.x = fmaxf(v.x, SLOPE * v.x);
                        v.y = fmaf(v.y, sc4.y, sh4.y); v.y = fmaxf(v.y, SLOPE * v.y);
                        v.z = fmaf(v.z, sc4.z, sh4.z); v.z = fmaxf(v.z, SLOPE * v.z);
                        v.w = fmaf(v.w, sc4.w, sh4.w); v.w = fmaxf(v.w, SLOPE * v.w);
                    }
                }
                *(float4*)&xs[r][cg] = v;
            }
        }
        __syncthreads();

        for (int mm = 0; mm < 4; ++mm) {
            int mrow = mm * 16 + (lane & 15);
            f32x4_t aL[2], aR[2], aS[2];
#pragma unroll
            for (int j = 0; j < 2; ++j) {
                aL[j] = (f32x4_t)0.f; aR[j] = (f32x4_t)0.f; aS[j] = (f32x4_t)0.f;
            }
#pragma unroll
            for (int ks = 0; ks < 4; ++ks) {
                const float* src = &xs[mrow][ks * 32 + koff];
                float4 f0 = *(const float4*)src;
                float4 f1 = *(const float4*)(src + 4);
                float f[8] = {f0.x, f0.y, f0.z, f0.w, f1.x, f1.y, f1.z, f1.w};
                bf16x8_t ah, al;
#pragma unroll
                for (int j = 0; j < 8; ++j) {
                    short hi = f2bf(f[j]);
                    unsigned int hu = ((unsigned int)(unsigned short)hi) << 16;
                    ah[j] = hi;
                    al[j] = f2bf(f[j] - __uint_as_float(hu));
                }
#pragma unroll
                for (int j = 0; j < 2; ++j) {
                    aL[j] = __builtin_amdgcn_mfma_f32_16x16x32_bf16(ah, bL[ks][j], aL[j], 0, 0, 0);
                    aL[j] = __builtin_amdgcn_mfma_f32_16x16x32_bf16(al, bL[ks][j], aL[j], 0, 0, 0);
                    aR[j] = __builtin_amdgcn_mfma_f32_16x16x32_bf16(ah, bR[ks][j], aR[j], 0, 0, 0);
                    aR[j] = __builtin_amdgcn_mfma_f32_16x16x32_bf16(al, bR[ks][j], aR[j], 0, 0, 0);
                    aS[j] = __builtin_amdgcn_mfma_f32_16x16x32_bf16(ah, bS[ks][j], aS[j], 0, 0, 0);
                    aS[j] = __builtin_amdgcn_mfma_f32_16x16x32_bf16(al, bS[ks][j], aS[j], 0, 0, 0);
                }
            }
            // C/D layout: col = lane&15, row = (lane>>4)*4 + r
            int rowq = row0 + mm * 16 + (lane >> 4) * 4;
#pragma unroll
            for (int j = 0; j < 2; ++j) {
                int n = (nb0 + j) * 16 + col;
                float bv = bias[n];
#pragma unroll
                for (int r = 0; r < 4; ++r) {
                    int row = rowq + r;
                    if (row < N) {
                        xl[(size_t)row * D + n] = __float2bfloat16(aL[j][r]);
                        xr[(size_t)row * D + n] = aR[j][r];
                        y[(size_t)row * D + n]  = aS[j][r] + bv;
                    }
                }
            }
        }
    }
}

// ---------- final linear via MFMA, same persistent structure (BN+leaky on load) ----------
__global__ __launch_bounds__(256) void gemm_out_mfma_kernel(
        const float* __restrict__ x, const float* __restrict__ ss,
        const hbf* __restrict__ Wph, const float* __restrict__ b,
        float* __restrict__ out) {
    __shared__ float xs[64][133];
    int t = threadIdx.x;
    int wave = t >> 6;
    int lane = t & 63;
    int nb0 = wave * 2;

    const bf16x8_t* B = (const bf16x8_t*)Wph + 9 * 2048;      // matrix 9 = Wout
    bf16x8_t bW[4][2];
#pragma unroll
    for (int ks = 0; ks < 4; ++ks)
#pragma unroll
        for (int j = 0; j < 2; ++j)
            bW[ks][j] = B[(ks * 8 + nb0 + j) * 64 + lane];

    int cg = (t & 31) * 4;
    float4 sc4 = *(const float4*)(ss + cg);
    float4 sh4 = *(const float4*)(ss + D + cg);
    int col = lane & 15;
    int koff = (lane >> 4) * 8;

    for (int tt = blockIdx.x; tt < TILES; tt += gridDim.x) {
        int row0 = tt * 64;
        __syncthreads();
        {
            const float4* x4 = (const float4*)(x + (size_t)row0 * D);
            for (int i = t; i < 64 * 32; i += 256) {
                int r = i >> 5;
                float4 v = make_float4(0.f, 0.f, 0.f, 0.f);
                if (row0 + r < N) {
                    v = x4[i];
                    v.x = fmaf(v.x, sc4.x, sh4.x); v.x = fmaxf(v.x, SLOPE * v.x);
                    v.y = fmaf(v.y, sc4.y, sh4.y); v.y = fmaxf(v.y, SLOPE * v.y);
                    v.z = fmaf(v.z, sc4.z, sh4.z); v.z = fmaxf(v.z, SLOPE * v.z);
                    v.w = fmaf(v.w, sc4.w, sh4.w); v.w = fmaxf(v.w, SLOPE * v.w);
                }
                *(float4*)&xs[r][cg] = v;
            }
        }
        __syncthreads();

        for (int mm = 0; mm < 4; ++mm) {
            int mrow = mm * 16 + (lane & 15);
            f32x4_t acc[2];
            acc[0] = (f32x4_t)0.f; acc[1] = (f32x4_t)0.f;
#pragma unroll
            for (int ks = 0; ks < 4; ++ks) {
                const float* src = &xs[mrow][ks * 32 + koff];
                float4 f0 = *(const float4*)src;
                float4 f1 = *(const float4*)(src + 4);
                float f[8] = {f0.x, f0.y, f0.z, f0.w, f1.x, f1.y, f1.z, f1.w};
                bf16x8_t ah, al;
#pragma unroll
                for (int j = 0; j < 8; ++j) {
                    short hi = f2bf(f[j]);
                    unsigned int hu = ((unsigned int)(unsigned short)hi) << 16;
                    ah[j] = hi;
                    al[j] = f2bf(f[j] - __uint_as_float(hu));
                }
#pragma unroll
                for (int j = 0; j < 2; ++j) {
                    acc[j] = __builtin_amdgcn_mfma_f32_16x16x32_bf16(ah, bW[ks][j], acc[j], 0, 0, 0);
                    acc[j] = __builtin_amdgcn_mfma_f32_16x16x32_bf16(al, bW[ks][j], acc[j], 0, 0, 0);
                }
            }
            int rowq = row0 + mm * 16 + (lane >> 4) * 4;
#pragma unroll
            for (int j = 0; j < 2; ++j) {
                int n = (nb0 + j) * 16 + col;
                float bv = b[n];
#pragma unroll
                for (int r = 0; r < 4; ++r) {
                    int row = rowq + r;
                    if (row < N) out[(size_t)row * D + n] = acc[j][r] + bv;
                }
            }
        }
    }
}

// ---------- GATv2 aggregation, one wave per node, bf16 xl gather, 2-edge unroll ----------
__global__ __launch_bounds__(128) void gat_kernel(
        const hbf* __restrict__ xl, const float* __restrict__ xr,
        float* y, const int* __restrict__ row_ptr,
        const int* __restrict__ col_idx, const float* __restrict__ att) {
    int wave = threadIdx.x >> 6;
    int lane = threadIdx.x & 63;
    int v = blockIdx.x * 2 + wave;
    const unsigned int* xlp = (const unsigned int*)xl;        // bf16 pair per lane
    float2 xr_v = ((const float2*)xr)[v * 64 + lane];
    float2 a2 = ((const float2*)att)[lane];           // channels 2l,2l+1; head = lane/16
    int beg = row_ptr[v], end = row_ptr[v + 1];
    float m = -INFINITY, l = 0.f;
    float2 acc = make_float2(0.f, 0.f);
    unsigned int u0 = xlp[(size_t)col_idx[beg] * 64 + lane];  // degree >= 1
    unsigned int u1 = 0;
    if (beg + 1 < end) u1 = xlp[(size_t)col_idx[beg + 1] * 64 + lane];
    int idx = beg;
    for (; idx + 1 < end; idx += 2) {
        float2 xa = bfpair_to_f2(u0);
        float2 xb = bfpair_to_f2(u1);
        if (idx + 2 < end) u0 = xlp[(size_t)col_idx[idx + 2] * 64 + lane];
        if (idx + 3 < end) u1 = xlp[(size_t)col_idx[idx + 3] * 64 + lane];
        float2 pa, pb;
        pa.x = xa.x + xr_v.x; pa.y = xa.y + xr_v.y;
        pb.x = xb.x + xr_v.x; pb.y = xb.y + xr_v.y;
        pa.x = fmaxf(pa.x, SLOPE * pa.x); pa.y = fmaxf(pa.y, SLOPE * pa.y);
        pb.x = fmaxf(pb.x, SLOPE * pb.x); pb.y = fmaxf(pb.y, SLOPE * pb.y);
        float sa = fmaf(pa.x, a2.x, pa.y * a2.y);
        float sb = fmaf(pb.x, a2.x, pb.y * a2.y);
        sa += __shfl_xor(sa, 1);  sb += __shfl_xor(sb, 1);
        sa += __shfl_xor(sa, 2);  sb += __shfl_xor(sb, 2);
        sa += __shfl_xor(sa, 4);  sb += __shfl_xor(sb, 4);
        sa += __shfl_xor(sa, 8);  sb += __shfl_xor(sb, 8);
        float nm = fmaxf(m, fmaxf(sa, sb));
        float scl = __expf(m - nm);                   // 0 on first iter (m=-inf)
        float wa  = __expf(sa - nm);
        float wb  = __expf(sb - nm);
        l = fmaf(l, scl, wa + wb);
        acc.x = fmaf(wb, xb.x, fmaf(wa, xa.x, acc.x * scl));
        acc.y = fmaf(wb, xb.y, fmaf(wa, xa.y, acc.y * scl));
        m = nm;
    }
    if (idx < end) {                                  // odd tail, data in u0
        float2 xa = bfpair_to_f2(u0);
        float2 pa;
        pa.x = xa.x + xr_v.x; pa.y = xa.y + xr_v.y;
        pa.x = fmaxf(pa.x, SLOPE * pa.x); pa.y = fmaxf(pa.y, SLOPE * pa.y);
        float sa = fmaf(pa.x, a2.x, pa.y * a2.y);
        sa += __shfl_xor(sa, 1);
        sa += __shfl_xor(sa, 2);
        sa += __shfl_xor(sa, 4);
        sa += __shfl_xor(sa, 8);
        float nm = fmaxf(m, sa);
        float scl = __expf(m - nm);
        float wa  = __expf(sa - nm);
        l = fmaf(l, scl, wa);
        acc.x = fmaf(wa, xa.x, acc.x * scl);
        acc.y = fmaf(wa, xa.y, acc.y * scl);
    }
    float rl = 1.f / l;
    int o = v * 64 + lane;
    float2 yv = ((const float2*)y)[o];
    yv.x = fmaf(acc.x, rl, yv.x);                     // agg + res(+bias)
    yv.y = fmaf(acc.y, rl, yv.y);
    ((float2*)y)[o] = yv;
}

// ---------- BatchNorm stats: coalesced float4, LDS reduce, atomics ----------
__global__ __launch_bounds__(256) void bn_stats_kernel(const float* __restrict__ y,
                                                       float* __restrict__ sums) {
    __shared__ float ls[256][4];
    __shared__ float ls2[256][4];
    int t = threadIdx.x;
    float4 s = make_float4(0.f, 0.f, 0.f, 0.f);
    float4 s2 = make_float4(0.f, 0.f, 0.f, 0.f);
    const float4* y4 = (const float4*)y;
    for (int i = blockIdx.x * 256 + t; i < N * D / 4; i += gridDim.x * 256) {
        float4 v = y4[i];                             // cols 4*(t&31)..+3 (fixed)
        s.x += v.x; s.y += v.y; s.z += v.z; s.w += v.w;
        s2.x = fmaf(v.x, v.x, s2.x); s2.y = fmaf(v.y, v.y, s2.y);
        s2.z = fmaf(v.z, v.z, s2.z); s2.w = fmaf(v.w, v.w, s2.w);
    }
    ls[t][0] = s.x;  ls[t][1] = s.y;  ls[t][2] = s.z;  ls[t][3] = s.w;
    ls2[t][0] = s2.x; ls2[t][1] = s2.y; ls2[t][2] = s2.z; ls2[t][3] = s2.w;
    __syncthreads();
    if (t < D) {
        int g = t >> 2, e = t & 3;
        float a = 0.f, b = 0.f;
#pragma unroll
        for (int j = 0; j < 8; ++j) {
            a += ls[g + 32 * j][e];
            b += ls2[g + 32 * j][e];
        }
        atomicAdd(&sums[t], a);
        atomicAdd(&sums[D + t], b);
    }
}

__global__ __launch_bounds__(128) void bn_finalize_kernel(const float* __restrict__ sums,
                                                          const float* __restrict__ gamma,
                                                          const float* __restrict__ beta,
                                                          float* __restrict__ ss) {
    int t = threadIdx.x;
    float mean = sums[t] * (1.0f / N);
    float var = sums[D + t] * (1.0f / N) - mean * mean;
    var = fmaxf(var, 0.f);
    float sc = gamma[t] * rsqrtf(var + BN_EPS);
    ss[t] = sc;
    ss[D + t] = beta[t] - mean * sc;
}

extern "C" void kernel_launch(void* const* d_in, const int* in_sizes, int n_in,
                              void* d_out, int out_size, void* d_ws, size_t ws_size,
                              hipStream_t stream) {
    const float* x_in  = (const float*)d_in[0];
    const int*   ei    = (const int*)d_in[1];
    const float* Wl    = (const float*)d_in[2];
    const float* Wr    = (const float*)d_in[3];
    const float* att   = (const float*)d_in[4];
    const float* bias  = (const float*)d_in[5];
    const float* Wres  = (const float*)d_in[6];
    const float* gamma = (const float*)d_in[7];
    const float* beta  = (const float*)d_in[8];
    const float* Wout  = (const float*)d_in[9];
    const float* bout  = (const float*)d_in[10];
    float* out = (float*)d_out;

    char* ws = (char*)d_ws;
    size_t off = 0;
    auto alloc = [&](size_t bytes) {
        void* p = ws + off;
        off = (off + bytes + 255) & ~(size_t)255;
        return p;
    };
    hbf*   xl       = (hbf*)alloc((size_t)N * D * sizeof(hbf));
    float* xr       = (float*)alloc((size_t)N * D * sizeof(float));
    float* y        = (float*)alloc((size_t)N * D * sizeof(float));
    hbf*   Wph      = (hbf*)alloc((size_t)10 * D * D * sizeof(hbf));
    int*   row_ptr  = (int*)alloc((size_t)(N + 1) * sizeof(int));
    int*   col_idx  = (int*)alloc((size_t)E2 * sizeof(int));
    int*   counts   = (int*)alloc((size_t)N * sizeof(int));   // reused as write ptr
    int*   blk_sums = (int*)alloc(128 * sizeof(int));
    float* sums     = (float*)alloc(2 * D * sizeof(float));
    float* ss       = (float*)alloc(2 * D * sizeof(float));

    const int NB = (N + 511) / 512;                  // 98 scan blocks

    // CSR build + weight packing
    hipMemsetAsync(counts, 0, (size_t)N * sizeof(int), stream);
    count_kernel<<<(E2 + 255) / 256, 256, 0, stream>>>(ei, counts);
    pack_w_kernel<<<10 * 16384 / 256, 256, 0, stream>>>(Wl, Wr, Wres, Wout, Wph);
    scan_block_kernel<<<NB, 512, 0, stream>>>(counts, row_ptr, blk_sums);
    scan_sums_kernel<<<1, 128, 0, stream>>>(blk_sums, NB);
    scan_add_kernel<<<(N + 255) / 256, 256, 0, stream>>>(row_ptr, blk_sums);
    hipMemsetAsync(counts, 0, (size_t)N * sizeof(int), stream);
    scatter_kernel<<<(E2 + 255) / 256, 256, 0, stream>>>(ei, row_ptr, counts, col_idx);

    for (int i = 0; i < L; ++i) {
        const float* xin = (i == 0) ? x_in : y;      // in-place (tile snapshot) for 1,2
        const float* ssi = (i == 0) ? nullptr : ss;  // BN(i-1)+leaky fused into staging
        gemm3_mfma_kernel<<<256, 256, 0, stream>>>(xin, ssi, Wph, i, 3 + i, 6 + i,
                                                   bias + (size_t)i * D, xl, xr, y);
        gat_kernel<<<N / 2, 128, 0, stream>>>(xl, xr, y, row_ptr, col_idx,
                                              att + (size_t)i * H * C);
        hipMemsetAsync(sums, 0, 2 * D * sizeof(float), stream);
        bn_stats_kernel<<<1024, 256, 0, stream>>>(y, sums);
        bn_finalize_kernel<<<1, 128, 0, stream>>>(sums, gamma + (size_t)i * D,
                                                  beta + (size_t)i * D, ss);
    }

    gemm_out_mfma_kernel<<<256, 256, 0, stream>>>(y, ss, Wph, bout, out);
}

// Round 9
// 576.488 us; speedup vs baseline: 1.7901x; 1.1880x over previous
//
#include <hip/hip_runtime.h>
#include <hip/hip_bf16.h>

constexpr int N = 50000;
constexpr int E = 800000;
constexpr int D = 128;
constexpr int H = 4;
constexpr int C = 32;
constexpr int L = 3;
constexpr int E2 = E + N;           // edges + self loops
constexpr float SLOPE = 0.2f;
constexpr float BN_EPS = 1e-5f;
constexpr float LOG2E = 1.4426950408889634f;
constexpr int TILES = (N + 63) / 64;                 // 782 row tiles

typedef __attribute__((ext_vector_type(8))) short bf16x8_t;   // 8 bf16 (4 VGPRs)
typedef __attribute__((ext_vector_type(4))) float f32x4_t;    // MFMA C/D

using hbf = __hip_bfloat16;

__device__ __forceinline__ float fast_exp2(float x) { return __builtin_amdgcn_exp2f(x); }

__device__ __forceinline__ short f2bf(float v) {
    hbf h = __float2bfloat16(v);
    return *reinterpret_cast<short*>(&h);
}
__device__ __forceinline__ float2 bfpair_to_f2(unsigned int u) {
    float2 r;
    r.x = __uint_as_float(u << 16);
    r.y = __uint_as_float(u & 0xffff0000u);
    return r;
}

// ---------- CSR build ----------
__global__ void count_kernel(const int* __restrict__ ei, int* __restrict__ counts) {
    int i = blockIdx.x * blockDim.x + threadIdx.x;
    if (i >= E2) return;
    int dst = (i < E) ? ei[E + i] : (i - E);
    atomicAdd(&counts[dst], 1);
}

__global__ __launch_bounds__(512) void scan_block_kernel(const int* __restrict__ counts,
                                                         int* __restrict__ row_ptr,
                                                         int* __restrict__ blk_sums) {
    __shared__ int s[512];
    int t = threadIdx.x;
    int i = blockIdx.x * 512 + t;
    int v = (i < N) ? counts[i] : 0;
    s[t] = v;
    __syncthreads();
    for (int off = 1; off < 512; off <<= 1) {
        int add = (t >= off) ? s[t - off] : 0;
        __syncthreads();
        s[t] += add;
        __syncthreads();
    }
    if (i < N) row_ptr[i] = s[t] - v;                 // exclusive within block
    if (t == 511) blk_sums[blockIdx.x] = s[511];
}

__global__ __launch_bounds__(128) void scan_sums_kernel(int* __restrict__ blk, int nb) {
    __shared__ int s[128];
    int t = threadIdx.x;
    int v = (t < nb) ? blk[t] : 0;
    s[t] = v;
    __syncthreads();
    for (int off = 1; off < 128; off <<= 1) {
        int add = (t >= off) ? s[t - off] : 0;
        __syncthreads();
        s[t] += add;
        __syncthreads();
    }
    if (t < nb) blk[t] = s[t] - v;                    // exclusive block offsets
}

__global__ void scan_add_kernel(int* __restrict__ row_ptr, const int* __restrict__ blk) {
    int i = blockIdx.x * blockDim.x + threadIdx.x;
    if (i < N) row_ptr[i] += blk[i >> 9];
    if (i == 0) row_ptr[N] = E2;
}

__global__ void scatter_kernel(const int* __restrict__ ei, const int* __restrict__ row_ptr,
                               int* __restrict__ wp, int* __restrict__ col_idx) {
    int i = blockIdx.x * blockDim.x + threadIdx.x;
    if (i >= E2) return;
    int src, dst;
    if (i < E) { src = ei[i]; dst = ei[E + i]; }
    else       { src = i - E; dst = i - E; }
    int pos = row_ptr[dst] + atomicAdd(&wp[dst], 1);
    col_idx[pos] = src;
}

// ---------- pack 10 weight matrices into MFMA B-fragment order (hi bf16 only) ----------
// B frag for 16x16x32: lane holds B[k = ks*32 + (lane>>4)*8 + j][n = nb*16 + (lane&15)],
// j=0..7. Packed index: (mat*2048 + (ks*8+nb)*64 + lane)*8 + j  -> lane-contiguous 16B.
__global__ __launch_bounds__(256) void pack_w_kernel(
        const float* __restrict__ Wl, const float* __restrict__ Wr,
        const float* __restrict__ Wres, const float* __restrict__ Wout,
        hbf* __restrict__ Wph) {
    int gid = blockIdx.x * 256 + threadIdx.x;        // 10 * 16384
    int mat = gid >> 14;
    int d = gid & 16383;
    const float* W;
    if (mat < 3)      W = Wl + (size_t)mat * 16384;
    else if (mat < 6) W = Wr + (size_t)(mat - 3) * 16384;
    else if (mat < 9) W = Wres + (size_t)(mat - 6) * 16384;
    else              W = Wout;
    int j = d & 7, lane = (d >> 3) & 63, nb = (d >> 9) & 7, ks = d >> 12;
    int k = ks * 32 + ((lane >> 4) * 8) + j;
    int n = nb * 16 + (lane & 15);
    Wph[gid] = __float2bfloat16(W[k * D + n]);
}

// ---------- fused 3-matrix MFMA GEMM, one 64-row tile per block ----------
// X = leaky(bn(x)) if sums else x; bn scale/shift derived in-block from sums+gamma+beta.
// xl = bf16(X@Wl), xr = X@Wr, y = X@Wres + bias.  In-place-safe (x == y): tile is
// snapshot into LDS before any store; each tile owned by one block.
// Wave w owns n-blocks {2w, 2w+1}; B frags (24) in VGPRs, loaded once per block.
// 2-term split: X@W ~= Xh@Wh + Xl@Wh (W bf16-rounded).
__global__ __launch_bounds__(256) void gemm3_mfma_kernel(
        const float* x, const float* __restrict__ sums,
        const float* __restrict__ gamma, const float* __restrict__ beta,
        const hbf* __restrict__ Wph,
        int mL, int mR, int mS, const float* __restrict__ bias,
        hbf* __restrict__ xl, float* __restrict__ xr, float* y) {
    __shared__ float xs[64][133];                     // +5 pad: 2-way max bank aliasing
    __shared__ float ssl[2][128];                     // bn scale/shift
    int t = threadIdx.x;
    int wave = t >> 6;
    int lane = t & 63;
    int nb0 = wave * 2;                               // this wave's two n-blocks
    int row0 = blockIdx.x * 64;

    if (sums && t < 128) {                            // fold of old bn_finalize
        float mean = sums[t] * (1.0f / N);
        float var = fmaxf(sums[D + t] * (1.0f / N) - mean * mean, 0.f);
        float sc = gamma[t] * rsqrtf(var + BN_EPS);
        ssl[0][t] = sc;
        ssl[1][t] = beta[t] - mean * sc;
    }

    const bf16x8_t* B = (const bf16x8_t*)Wph;
    bf16x8_t bL[4][2], bR[4][2], bS[4][2];            // 24 frags = 96 VGPRs, loaded once
#pragma unroll
    for (int ks = 0; ks < 4; ++ks)
#pragma unroll
        for (int j = 0; j < 2; ++j) {
            int bo = (ks * 8 + nb0 + j) * 64 + lane;
            bL[ks][j] = B[mL * 2048 + bo];
            bR[ks][j] = B[mR * 2048 + bo];
            bS[ks][j] = B[mS * 2048 + bo];
        }
    __syncthreads();                                  // ssl visible

    int cg = (t & 31) * 4;                            // staging col group
    {
        float sc_[4] = {1.f, 1.f, 1.f, 1.f}, sh_[4] = {0.f, 0.f, 0.f, 0.f};
        if (sums) {
#pragma unroll
            for (int j = 0; j < 4; ++j) { sc_[j] = ssl[0][cg + j]; sh_[j] = ssl[1][cg + j]; }
        }
        const float4* x4 = (const float4*)(x + (size_t)row0 * D);
        for (int i = t; i < 64 * 32; i += 256) {
            int r = i >> 5;
            float4 v = make_float4(0.f, 0.f, 0.f, 0.f);
            if (row0 + r < N) {
                v = x4[i];
                if (sums) {
                    v.x = fmaf(v.x, sc_[0], sh_[0]); v.x = fmaxf(v.x, SLOPE * v.x);
                    v.y = fmaf(v.y, sc_[1], sh_[1]); v.y = fmaxf(v.y, SLOPE * v.y);
                    v.z = fmaf(v.z, sc_[2], sh_[2]); v.z = fmaxf(v.z, SLOPE * v.z);
                    v.w = fmaf(v.w, sc_[3], sh_[3]); v.w = fmaxf(v.w, SLOPE * v.w);
                }
            }
            *(float4*)&xs[r][cg] = v;
        }
    }
    __syncthreads();

    int col = lane & 15;
    int koff = (lane >> 4) * 8;
    for (int mm = 0; mm < 4; ++mm) {
        int mrow = mm * 16 + (lane & 15);
        f32x4_t aL[2], aR[2], aS[2];
#pragma unroll
        for (int j = 0; j < 2; ++j) {
            aL[j] = (f32x4_t)0.f; aR[j] = (f32x4_t)0.f; aS[j] = (f32x4_t)0.f;
        }
#pragma unroll
        for (int ks = 0; ks < 4; ++ks) {
            const float* src = &xs[mrow][ks * 32 + koff];
            float4 f0 = *(const float4*)src;
            float4 f1 = *(const float4*)(src + 4);
            float f[8] = {f0.x, f0.y, f0.z, f0.w, f1.x, f1.y, f1.z, f1.w};
            bf16x8_t ah, al;
#pragma unroll
            for (int j = 0; j < 8; ++j) {
                short hi = f2bf(f[j]);
                unsigned int hu = ((unsigned int)(unsigned short)hi) << 16;
                ah[j] = hi;
                al[j] = f2bf(f[j] - __uint_as_float(hu));
            }
#pragma unroll
            for (int j = 0; j < 2; ++j) {
                aL[j] = __builtin_amdgcn_mfma_f32_16x16x32_bf16(ah, bL[ks][j], aL[j], 0, 0, 0);
                aL[j] = __builtin_amdgcn_mfma_f32_16x16x32_bf16(al, bL[ks][j], aL[j], 0, 0, 0);
                aR[j] = __builtin_amdgcn_mfma_f32_16x16x32_bf16(ah, bR[ks][j], aR[j], 0, 0, 0);
                aR[j] = __builtin_amdgcn_mfma_f32_16x16x32_bf16(al, bR[ks][j], aR[j], 0, 0, 0);
                aS[j] = __builtin_amdgcn_mfma_f32_16x16x32_bf16(ah, bS[ks][j], aS[j], 0, 0, 0);
                aS[j] = __builtin_amdgcn_mfma_f32_16x16x32_bf16(al, bS[ks][j], aS[j], 0, 0, 0);
            }
        }
        // C/D layout: col = lane&15, row = (lane>>4)*4 + r
        int rowq = row0 + mm * 16 + (lane >> 4) * 4;
#pragma unroll
        for (int j = 0; j < 2; ++j) {
            int n = (nb0 + j) * 16 + col;
            float bv = bias[n];
#pragma unroll
            for (int r = 0; r < 4; ++r) {
                int row = rowq + r;
                if (row < N) {
                    xl[(size_t)row * D + n] = __float2bfloat16(aL[j][r]);
                    xr[(size_t)row * D + n] = aR[j][r];
                    y[(size_t)row * D + n]  = aS[j][r] + bv;
                }
            }
        }
    }
}

// ---------- final linear via MFMA, same structure (BN+leaky on load) ----------
__global__ __launch_bounds__(256) void gemm_out_mfma_kernel(
        const float* __restrict__ x, const float* __restrict__ sums,
        const float* __restrict__ gamma, const float* __restrict__ beta,
        const hbf* __restrict__ Wph, const float* __restrict__ b,
        float* __restrict__ out) {
    __shared__ float xs[64][133];
    __shared__ float ssl[2][128];
    int t = threadIdx.x;
    int wave = t >> 6;
    int lane = t & 63;
    int nb0 = wave * 2;
    int row0 = blockIdx.x * 64;

    if (t < 128) {
        float mean = sums[t] * (1.0f / N);
        float var = fmaxf(sums[D + t] * (1.0f / N) - mean * mean, 0.f);
        float sc = gamma[t] * rsqrtf(var + BN_EPS);
        ssl[0][t] = sc;
        ssl[1][t] = beta[t] - mean * sc;
    }

    const bf16x8_t* B = (const bf16x8_t*)Wph + 9 * 2048;      // matrix 9 = Wout
    bf16x8_t bW[4][2];
#pragma unroll
    for (int ks = 0; ks < 4; ++ks)
#pragma unroll
        for (int j = 0; j < 2; ++j)
            bW[ks][j] = B[(ks * 8 + nb0 + j) * 64 + lane];
    __syncthreads();

    int cg = (t & 31) * 4;
    {
        float sc_[4], sh_[4];
#pragma unroll
        for (int j = 0; j < 4; ++j) { sc_[j] = ssl[0][cg + j]; sh_[j] = ssl[1][cg + j]; }
        const float4* x4 = (const float4*)(x + (size_t)row0 * D);
        for (int i = t; i < 64 * 32; i += 256) {
            int r = i >> 5;
            float4 v = make_float4(0.f, 0.f, 0.f, 0.f);
            if (row0 + r < N) {
                v = x4[i];
                v.x = fmaf(v.x, sc_[0], sh_[0]); v.x = fmaxf(v.x, SLOPE * v.x);
                v.y = fmaf(v.y, sc_[1], sh_[1]); v.y = fmaxf(v.y, SLOPE * v.y);
                v.z = fmaf(v.z, sc_[2], sh_[2]); v.z = fmaxf(v.z, SLOPE * v.z);
                v.w = fmaf(v.w, sc_[3], sh_[3]); v.w = fmaxf(v.w, SLOPE * v.w);
            }
            *(float4*)&xs[r][cg] = v;
        }
    }
    __syncthreads();

    int col = lane & 15;
    int koff = (lane >> 4) * 8;
    for (int mm = 0; mm < 4; ++mm) {
        int mrow = mm * 16 + (lane & 15);
        f32x4_t acc[2];
        acc[0] = (f32x4_t)0.f; acc[1] = (f32x4_t)0.f;
#pragma unroll
        for (int ks = 0; ks < 4; ++ks) {
            const float* src = &xs[mrow][ks * 32 + koff];
            float4 f0 = *(const float4*)src;
            float4 f1 = *(const float4*)(src + 4);
            float f[8] = {f0.x, f0.y, f0.z, f0.w, f1.x, f1.y, f1.z, f1.w};
            bf16x8_t ah, al;
#pragma unroll
            for (int j = 0; j < 8; ++j) {
                short hi = f2bf(f[j]);
                unsigned int hu = ((unsigned int)(unsigned short)hi) << 16;
                ah[j] = hi;
                al[j] = f2bf(f[j] - __uint_as_float(hu));
            }
#pragma unroll
            for (int j = 0; j < 2; ++j) {
                acc[j] = __builtin_amdgcn_mfma_f32_16x16x32_bf16(ah, bW[ks][j], acc[j], 0, 0, 0);
                acc[j] = __builtin_amdgcn_mfma_f32_16x16x32_bf16(al, bW[ks][j], acc[j], 0, 0, 0);
            }
        }
        int rowq = row0 + mm * 16 + (lane >> 4) * 4;
#pragma unroll
        for (int j = 0; j < 2; ++j) {
            int n = (nb0 + j) * 16 + col;
            float bv = b[n];
#pragma unroll
            for (int r = 0; r < 4; ++r) {
                int row = rowq + r;
                if (row < N) out[(size_t)row * D + n] = acc[j][r] + bv;
            }
        }
    }
}

// ---------- GATv2 aggregation, one wave per node, bf16 xl gather, 4-edge unroll ----------
// Scores in log2 domain (att pre-scaled by log2e) -> exp2, exact same softmax weights.
__global__ __launch_bounds__(128) void gat_kernel(
        const hbf* __restrict__ xl, const float* __restrict__ xr,
        float* y, const int* __restrict__ row_ptr,
        const int* __restrict__ col_idx, const float* __restrict__ att) {
    int wave = threadIdx.x >> 6;
    int lane = threadIdx.x & 63;
    int v = blockIdx.x * 2 + wave;
    const unsigned int* xlp = (const unsigned int*)xl;        // bf16 pair per lane
    float2 xr_v = ((const float2*)xr)[v * 64 + lane];
    float2 a2 = ((const float2*)att)[lane];           // channels 2l,2l+1; head = lane/16
    a2.x *= LOG2E; a2.y *= LOG2E;
    int beg = row_ptr[v], end = row_ptr[v + 1];
    float m = -INFINITY, l = 0.f;
    float2 acc = make_float2(0.f, 0.f);

    unsigned int u[4];
#pragma unroll
    for (int k = 0; k < 4; ++k)
        u[k] = (beg + k < end) ? xlp[(size_t)col_idx[beg + k] * 64 + lane] : 0u;

    int idx = beg;
    for (; idx + 3 < end; idx += 4) {
        float2 x0 = bfpair_to_f2(u[0]);
        float2 x1 = bfpair_to_f2(u[1]);
        float2 x2 = bfpair_to_f2(u[2]);
        float2 x3 = bfpair_to_f2(u[3]);
#pragma unroll
        for (int k = 0; k < 4; ++k) {                 // prefetch next 4
            int nx = idx + 4 + k;
            if (nx < end) u[k] = xlp[(size_t)col_idx[nx] * 64 + lane];
        }
        float2 p0, p1, p2, p3;
        p0.x = x0.x + xr_v.x; p0.y = x0.y + xr_v.y;
        p1.x = x1.x + xr_v.x; p1.y = x1.y + xr_v.y;
        p2.x = x2.x + xr_v.x; p2.y = x2.y + xr_v.y;
        p3.x = x3.x + xr_v.x; p3.y = x3.y + xr_v.y;
        p0.x = fmaxf(p0.x, SLOPE * p0.x); p0.y = fmaxf(p0.y, SLOPE * p0.y);
        p1.x = fmaxf(p1.x, SLOPE * p1.x); p1.y = fmaxf(p1.y, SLOPE * p1.y);
        p2.x = fmaxf(p2.x, SLOPE * p2.x); p2.y = fmaxf(p2.y, SLOPE * p2.y);
        p3.x = fmaxf(p3.x, SLOPE * p3.x); p3.y = fmaxf(p3.y, SLOPE * p3.y);
        float s0 = fmaf(p0.x, a2.x, p0.y * a2.y);
        float s1 = fmaf(p1.x, a2.x, p1.y * a2.y);
        float s2 = fmaf(p2.x, a2.x, p2.y * a2.y);
        float s3 = fmaf(p3.x, a2.x, p3.y * a2.y);
        s0 += __shfl_xor(s0, 1); s1 += __shfl_xor(s1, 1);
        s2 += __shfl_xor(s2, 1); s3 += __shfl_xor(s3, 1);
        s0 += __shfl_xor(s0, 2); s1 += __shfl_xor(s1, 2);
        s2 += __shfl_xor(s2, 2); s3 += __shfl_xor(s3, 2);
        s0 += __shfl_xor(s0, 4); s1 += __shfl_xor(s1, 4);
        s2 += __shfl_xor(s2, 4); s3 += __shfl_xor(s3, 4);
        s0 += __shfl_xor(s0, 8); s1 += __shfl_xor(s1, 8);
        s2 += __shfl_xor(s2, 8); s3 += __shfl_xor(s3, 8);
        float nm = fmaxf(fmaxf(m, fmaxf(s0, s1)), fmaxf(s2, s3));
        float scl = fast_exp2(m - nm);                // 0 on first iter (m=-inf)
        float w0 = fast_exp2(s0 - nm);
        float w1 = fast_exp2(s1 - nm);
        float w2 = fast_exp2(s2 - nm);
        float w3 = fast_exp2(s3 - nm);
        l = fmaf(l, scl, (w0 + w1) + (w2 + w3));
        acc.x = fmaf(w3, x3.x, fmaf(w2, x2.x, fmaf(w1, x1.x, fmaf(w0, x0.x, acc.x * scl))));
        acc.y = fmaf(w3, x3.y, fmaf(w2, x2.y, fmaf(w1, x1.y, fmaf(w0, x0.y, acc.y * scl))));
        m = nm;
    }
    for (int k = 0; idx < end; ++idx, ++k) {          // tail 0-3 edges, data in u[k]
        float2 xa = bfpair_to_f2(u[k]);
        float2 pa;
        pa.x = xa.x + xr_v.x; pa.y = xa.y + xr_v.y;
        pa.x = fmaxf(pa.x, SLOPE * pa.x); pa.y = fmaxf(pa.y, SLOPE * pa.y);
        float sa = fmaf(pa.x, a2.x, pa.y * a2.y);
        sa += __shfl_xor(sa, 1);
        sa += __shfl_xor(sa, 2);
        sa += __shfl_xor(sa, 4);
        sa += __shfl_xor(sa, 8);
        float nm = fmaxf(m, sa);
        float scl = fast_exp2(m - nm);
        float wa  = fast_exp2(sa - nm);
        l = fmaf(l, scl, wa);
        acc.x = fmaf(wa, xa.x, acc.x * scl);
        acc.y = fmaf(wa, xa.y, acc.y * scl);
        m = nm;
    }
    float rl = 1.f / l;
    int o = v * 64 + lane;
    float2 yv = ((const float2*)y)[o];
    yv.x = fmaf(acc.x, rl, yv.x);                     // agg + res(+bias)
    yv.y = fmaf(acc.y, rl, yv.y);
    ((float2*)y)[o] = yv;
}

// ---------- BatchNorm stats: coalesced float4, LDS reduce, atomics ----------
__global__ __launch_bounds__(256) void bn_stats_kernel(const float* __restrict__ y,
                                                       float* __restrict__ sums) {
    __shared__ float ls[256][4];
    __shared__ float ls2[256][4];
    int t = threadIdx.x;
    float4 s = make_float4(0.f, 0.f, 0.f, 0.f);
    float4 s2 = make_float4(0.f, 0.f, 0.f, 0.f);
    const float4* y4 = (const float4*)y;
    for (int i = blockIdx.x * 256 + t; i < N * D / 4; i += gridDim.x * 256) {
        float4 v = y4[i];                             // cols 4*(t&31)..+3 (fixed)
        s.x += v.x; s.y += v.y; s.z += v.z; s.w += v.w;
        s2.x = fmaf(v.x, v.x, s2.x); s2.y = fmaf(v.y, v.y, s2.y);
        s2.z = fmaf(v.z, v.z, s2.z); s2.w = fmaf(v.w, v.w, s2.w);
    }
    ls[t][0] = s.x;  ls[t][1] = s.y;  ls[t][2] = s.z;  ls[t][3] = s.w;
    ls2[t][0] = s2.x; ls2[t][1] = s2.y; ls2[t][2] = s2.z; ls2[t][3] = s2.w;
    __syncthreads();
    if (t < D) {
        int g = t >> 2, e = t & 3;
        float a = 0.f, b = 0.f;
#pragma unroll
        for (int j = 0; j < 8; ++j) {
            a += ls[g + 32 * j][e];
            b += ls2[g + 32 * j][e];
        }
        atomicAdd(&sums[t], a);
        atomicAdd(&sums[D + t], b);
    }
}

extern "C" void kernel_launch(void* const* d_in, const int* in_sizes, int n_in,
                              void* d_out, int out_size, void* d_ws, size_t ws_size,
                              hipStream_t stream) {
    const float* x_in  = (const float*)d_in[0];
    const int*   ei    = (const int*)d_in[1];
    const float* Wl    = (const float*)d_in[2];
    const float* Wr    = (const float*)d_in[3];
    const float* att   = (const float*)d_in[4];
    const float* bias  = (const float*)d_in[5];
    const float* Wres  = (const float*)d_in[6];
    const float* gamma = (const float*)d_in[7];
    const float* beta  = (const float*)d_in[8];
    const float* Wout  = (const float*)d_in[9];
    const float* bout  = (const float*)d_in[10];
    float* out = (float*)d_out;

    char* ws = (char*)d_ws;
    size_t off = 0;
    auto alloc = [&](size_t bytes) {
        void* p = ws + off;
        off = (off + bytes + 255) & ~(size_t)255;
        return p;
    };
    hbf*   xl       = (hbf*)alloc((size_t)N * D * sizeof(hbf));
    float* xr       = (float*)alloc((size_t)N * D * sizeof(float));
    float* y        = (float*)alloc((size_t)N * D * sizeof(float));
    hbf*   Wph      = (hbf*)alloc((size_t)10 * D * D * sizeof(hbf));
    int*   row_ptr  = (int*)alloc((size_t)(N + 1) * sizeof(int));
    int*   col_idx  = (int*)alloc((size_t)E2 * sizeof(int));
    int*   counts   = (int*)alloc((size_t)N * sizeof(int));   // reused as write ptr
    int*   blk_sums = (int*)alloc(128 * sizeof(int));
    float* sums     = (float*)alloc(2 * D * sizeof(float));

    const int NB = (N + 511) / 512;                  // 98 scan blocks

    // CSR build + weight packing
    (void)hipMemsetAsync(counts, 0, (size_t)N * sizeof(int), stream);
    count_kernel<<<(E2 + 255) / 256, 256, 0, stream>>>(ei, counts);
    pack_w_kernel<<<10 * 16384 / 256, 256, 0, stream>>>(Wl, Wr, Wres, Wout, Wph);
    scan_block_kernel<<<NB, 512, 0, stream>>>(counts, row_ptr, blk_sums);
    scan_sums_kernel<<<1, 128, 0, stream>>>(blk_sums, NB);
    scan_add_kernel<<<(N + 255) / 256, 256, 0, stream>>>(row_ptr, blk_sums);
    (void)hipMemsetAsync(counts, 0, (size_t)N * sizeof(int), stream);
    scatter_kernel<<<(E2 + 255) / 256, 256, 0, stream>>>(ei, row_ptr, counts, col_idx);

    for (int i = 0; i < L; ++i) {
        const float* xin = (i == 0) ? x_in : y;      // in-place (tile snapshot) for 1,2
        const float* sm  = (i == 0) ? nullptr : sums;
        const float* ga  = (i == 0) ? nullptr : gamma + (size_t)(i - 1) * D;
        const float* be  = (i == 0) ? nullptr : beta + (size_t)(i - 1) * D;
        gemm3_mfma_kernel<<<TILES, 256, 0, stream>>>(xin, sm, ga, be, Wph,
                                                     i, 3 + i, 6 + i,
                                                     bias + (size_t)i * D, xl, xr, y);
        gat_kernel<<<N / 2, 128, 0, stream>>>(xl, xr, y, row_ptr, col_idx,
                                              att + (size_t)i * H * C);
        (void)hipMemsetAsync(sums, 0, 2 * D * sizeof(float), stream);
        bn_stats_kernel<<<512, 256, 0, stream>>>(y, sums);
    }

    gemm_out_mfma_kernel<<<TILES, 256, 0, stream>>>(y, sums, gamma + (size_t)2 * D,
                                                    beta + (size_t)2 * D, Wph, bout, out);
}